// Round 3
// baseline (1401.141 us; speedup 1.0000x reference)
//
#include <hip/hip_runtime.h>
#include <math.h>

// ---------- constants ----------
#define CDIM 192
#define HIDD 768

typedef float f32x4 __attribute__((ext_vector_type(4)));
typedef short bf16x8 __attribute__((ext_vector_type(8)));

__device__ __forceinline__ short f2bf(float f) {
  unsigned u = __builtin_bit_cast(unsigned, f);
  u = (u + 0x7FFFu + ((u >> 16) & 1u)) >> 16;
  return (short)u;
}
__device__ __forceinline__ float bf2f(short s) {
  unsigned u = ((unsigned)(unsigned short)s) << 16;
  return __builtin_bit_cast(float, u);
}
__device__ __forceinline__ float gelu_exact(float x) {
  return 0.5f * x * (1.0f + erff(x * 0.70710678118654752f));
}

// ---------- LayerNorm (fp32 in -> bf16 out), 4 rows/block ----------
__global__ __launch_bounds__(256) void ln_kernel(const float* __restrict__ x,
                                                 const float* __restrict__ w,
                                                 const float* __restrict__ b,
                                                 short* __restrict__ out) {
  int lane = threadIdx.x & 63;
  long row = (long)blockIdx.x * 4 + (threadIdx.x >> 6);
  const float* xr = x + row * CDIM;
  float v0 = xr[lane], v1 = xr[lane + 64], v2 = xr[lane + 128];
  float s = v0 + v1 + v2;
  float s2 = v0 * v0 + v1 * v1 + v2 * v2;
#pragma unroll
  for (int m = 1; m < 64; m <<= 1) {
    s += __shfl_xor(s, m);
    s2 += __shfl_xor(s2, m);
  }
  float mu = s * (1.0f / 192.0f);
  float rstd = rsqrtf(s2 * (1.0f / 192.0f) - mu * mu + 1e-5f);
  short* o = out + row * CDIM;
  o[lane] = f2bf((v0 - mu) * rstd * w[lane] + b[lane]);
  o[lane + 64] = f2bf((v1 - mu) * rstd * w[lane + 64] + b[lane + 64]);
  o[lane + 128] = f2bf((v2 - mu) * rstd * w[lane + 128] + b[lane + 128]);
}

// ---------- weight prep: W[K][N] fp32 -> Bt[N][K] bf16 ----------
__global__ __launch_bounds__(256) void wprep_kernel(const float* __restrict__ w,
                                                    short* __restrict__ bt,
                                                    int K, int N) {
  long i = (long)blockIdx.x * 256 + threadIdx.x;  // over N*K, bt-linear
  if (i >= (long)K * N) return;
  int n = (int)(i / K), k = (int)(i % K);
  bt[i] = f2bf(w[(long)k * N + n]);
}

// ---------- GEMM v2: one block = one M-tile; A staged ONCE; loop n-tiles ----
// out[M][NTOT] = A[M][KTOT](bf16) @ Bt^T + epilogue
// EPI 0: + bias(B0 cols<192 / B1 cols>=192) -> bf16   (qkv)
// EPI 1: + bias + resid(fp32)               -> fp32   (proj / l2)
// EPI 2: gelu(+ bias)                       -> bf16   (l1)
template <int BM, int KTOT, int NTOT, int EPI>
__global__ __launch_bounds__(256) void gemm_kernel(
    const short* __restrict__ A, const short* __restrict__ Bt,
    const float* __restrict__ B0, const float* __restrict__ B1,
    const float* __restrict__ resid, void* __restrict__ outp) {
  constexpr int KCH = KTOT / 192;
  constexpr int NT = NTOT / 64;
  constexpr int MREP = BM / 64;         // m-frags per wave
  constexpr int PH = BM * 24 / 256;     // staging phases (float4/thread)
  static_assert(KCH == 1 || MREP == 1, "KCH>1 path assumes BM=64");
  __shared__ short As[BM][200];  // pad: 400B row stride -> 2-way banks (free)
  const int tid = threadIdx.x;
  const int lane = tid & 63;
  const int wid = tid >> 6;
  const int lr = lane & 15;
  const int lg = lane >> 4;
  const long m0 = (long)blockIdx.x * BM;

  auto store4 = [&](int n, long rowb, const f32x4& v) {
#pragma unroll
    for (int r = 0; r < 4; ++r) {
      float val = v[r];
      long idx = (rowb + r) * NTOT + n;
      if constexpr (EPI == 0) {
        float bb = (n < 192) ? B0[n] : B1[n - 192];
        ((short*)outp)[idx] = f2bf(val + bb);
      } else if constexpr (EPI == 1) {
        ((float*)outp)[idx] = val + B0[n] + resid[idx];
      } else {
        ((short*)outp)[idx] = f2bf(gelu_exact(val + B0[n]));
      }
    }
  };

  if constexpr (KCH == 1) {
    // stage the full K=192 A-tile once (contiguous global region, coalesced)
#pragma unroll
    for (int p = 0; p < PH; ++p) {
      int ci = tid + p * 256;
      int r = ci / 24, c = ci % 24;
      *(float4*)(&As[r][c * 8]) = *(const float4*)(A + (m0 + r) * KTOT + c * 8);
    }
    __syncthreads();
#pragma unroll 1
    for (int nt = 0; nt < NT; ++nt) {
      const int n0 = nt * 64;
      f32x4 acc[MREP][4] = {};
#pragma unroll
      for (int ks = 0; ks < 6; ++ks) {
        bf16x8 bf[4];
#pragma unroll
        for (int ni = 0; ni < 4; ++ni)
          bf[ni] = *(const bf16x8*)(Bt + (long)(n0 + ni * 16 + lr) * KTOT +
                                    ks * 32 + lg * 8);
        bf16x8 a[MREP];
#pragma unroll
        for (int mi = 0; mi < MREP; ++mi)
          a[mi] = *(const bf16x8*)(&As[wid * 16 * MREP + mi * 16 + lr]
                                      [ks * 32 + lg * 8]);
#pragma unroll
        for (int mi = 0; mi < MREP; ++mi)
#pragma unroll
          for (int ni = 0; ni < 4; ++ni)
            acc[mi][ni] = __builtin_amdgcn_mfma_f32_16x16x32_bf16(
                a[mi], bf[ni], acc[mi][ni], 0, 0, 0);
      }
      // epilogue (C layout: col=lane&15, row=(lane>>4)*4+reg)
#pragma unroll
      for (int mi = 0; mi < MREP; ++mi)
#pragma unroll
        for (int ni = 0; ni < 4; ++ni)
          store4(n0 + ni * 16 + lr,
                 m0 + wid * 16 * MREP + mi * 16 + lg * 4, acc[mi][ni]);
    }
  } else {
    // K-chunked path (l2): hold all NT n-tiles' accumulators across kc
    f32x4 acc[NT][4] = {};
    for (int kc = 0; kc < KCH; ++kc) {
      __syncthreads();
#pragma unroll
      for (int p = 0; p < PH; ++p) {
        int ci = tid + p * 256;
        int r = ci / 24, c = ci % 24;
        *(float4*)(&As[r][c * 8]) =
            *(const float4*)(A + (m0 + r) * KTOT + kc * 192 + c * 8);
      }
      __syncthreads();
#pragma unroll
      for (int ks = 0; ks < 6; ++ks) {
        bf16x8 a = *(const bf16x8*)(&As[wid * 16 + lr][ks * 32 + lg * 8]);
#pragma unroll
        for (int nt = 0; nt < NT; ++nt)
#pragma unroll
          for (int ni = 0; ni < 4; ++ni) {
            bf16x8 bfv = *(const bf16x8*)(Bt +
                                          (long)(nt * 64 + ni * 16 + lr) * KTOT +
                                          kc * 192 + ks * 32 + lg * 8);
            acc[nt][ni] = __builtin_amdgcn_mfma_f32_16x16x32_bf16(
                a, bfv, acc[nt][ni], 0, 0, 0);
          }
      }
    }
#pragma unroll
    for (int nt = 0; nt < NT; ++nt)
#pragma unroll
      for (int ni = 0; ni < 4; ++ni)
        store4(nt * 64 + ni * 16 + lr, m0 + wid * 16 + lg * 4, acc[nt][ni]);
  }
}

// ---------- windowed attention: one wave per (batch, window, head) ----------
__global__ __launch_bounds__(64) void attn_kernel(const short* __restrict__ qkv,
                                                  const float* __restrict__ rpb,
                                                  short* __restrict__ y) {
  __shared__ short vT[32][72];  // [d][token]
  __shared__ short P[64][72];   // [q][k]
  const int lane = threadIdx.x;
  const int bid = blockIdx.x;
  const int h = bid % 6;
  const int w = (bid / 6) & 1023;
  const int b = bid / 6144;
  const int wr = w >> 5, wc = w & 31;
  const int lr = lane & 15, lg = lane >> 4;

  auto trow = [&](int t) -> long {  // token in (rolled) window -> original row
    int hr = wr * 8 + (t >> 3);
    int hc = wc * 8 + (t & 7);
    int ho = (hr + 4) & 255;
    int wo = (hc + 4) & 255;
    return (long)b * 65536 + ho * 256 + wo;
  };

  bf16x8 aq[4], bk[4];
#pragma unroll
  for (int i = 0; i < 4; ++i) {
    long rq = trow(i * 16 + lr);
    aq[i] = *(const bf16x8*)(qkv + rq * 576 + h * 32 + lg * 8);
    bk[i] = *(const bf16x8*)(qkv + rq * 576 + 192 + h * 32 + lg * 8);
  }
  {  // stage V transposed: vT[d][token]
    long rv = trow(lane);
    const short* vp = qkv + rv * 576 + 384 + h * 32;
#pragma unroll
    for (int q4 = 0; q4 < 4; ++q4) {
      bf16x8 vv = *(const bf16x8*)(vp + q4 * 8);
#pragma unroll
      for (int j = 0; j < 8; ++j) vT[q4 * 8 + j][lane] = vv[j];
    }
  }

  // S = Q @ K^T (head dim 32 = one K=32 MFMA)
  f32x4 s[4][4] = {};
#pragma unroll
  for (int mi = 0; mi < 4; ++mi)
#pragma unroll
    for (int ni = 0; ni < 4; ++ni)
      s[mi][ni] = __builtin_amdgcn_mfma_f32_16x16x32_bf16(aq[mi], bk[ni],
                                                          s[mi][ni], 0, 0, 0);

  const float SCALE = 0.17677669529663687f;
  float rinv[4][4];
#pragma unroll
  for (int mi = 0; mi < 4; ++mi) {
#pragma unroll
    for (int r = 0; r < 4; ++r) {
      int q = mi * 16 + lg * 4 + r;
      int qh = wr * 8 + (q >> 3), qw = wc * 8 + (q & 7);
      int ridq = 3 * ((qh < 248) ? 0 : ((qh < 252) ? 1 : 2)) +
                 ((qw < 248) ? 0 : ((qw < 252) ? 1 : 2));
      float lv[4];
      float mx = -1e30f;
#pragma unroll
      for (int ni = 0; ni < 4; ++ni) {
        int k = ni * 16 + lr;
        int dr = (q >> 3) - (k >> 3) + 7;
        int dc = (q & 7) - (k & 7) + 7;
        float bias = rpb[(dr * 15 + dc) * 6 + h];
        int kh = wr * 8 + (k >> 3), kw = wc * 8 + (k & 7);
        int ridk = 3 * ((kh < 248) ? 0 : ((kh < 252) ? 1 : 2)) +
                   ((kw < 248) ? 0 : ((kw < 252) ? 1 : 2));
        float lvv = s[mi][ni][r] * SCALE + bias + ((ridq != ridk) ? -100.0f : 0.0f);
        lv[ni] = lvv;
        mx = fmaxf(mx, lvv);
      }
#pragma unroll
      for (int m = 1; m < 16; m <<= 1) mx = fmaxf(mx, __shfl_xor(mx, m));
      float sum = 0.0f;
#pragma unroll
      for (int ni = 0; ni < 4; ++ni) {
        float p = expf(lv[ni] - mx);
        lv[ni] = p;
        sum += p;
      }
#pragma unroll
      for (int m = 1; m < 16; m <<= 1) sum += __shfl_xor(sum, m);
      rinv[mi][r] = 1.0f / sum;
#pragma unroll
      for (int ni = 0; ni < 4; ++ni) P[q][ni * 16 + lr] = f2bf(lv[ni]);
    }
  }
  __syncthreads();

  // O = P @ V (K=64 -> 2 steps)
  f32x4 o[4][2] = {};
#pragma unroll
  for (int ks = 0; ks < 2; ++ks) {
    bf16x8 ap[4], bv[2];
#pragma unroll
    for (int mi = 0; mi < 4; ++mi)
      ap[mi] = *(const bf16x8*)(&P[mi * 16 + lr][ks * 32 + lg * 8]);
#pragma unroll
    for (int ni = 0; ni < 2; ++ni)
      bv[ni] = *(const bf16x8*)(&vT[ni * 16 + lr][ks * 32 + lg * 8]);
#pragma unroll
    for (int mi = 0; mi < 4; ++mi)
#pragma unroll
      for (int ni = 0; ni < 2; ++ni)
        o[mi][ni] = __builtin_amdgcn_mfma_f32_16x16x32_bf16(ap[mi], bv[ni],
                                                            o[mi][ni], 0, 0, 0);
  }
#pragma unroll
  for (int mi = 0; mi < 4; ++mi) {
#pragma unroll
    for (int r = 0; r < 4; ++r) {
      int q = mi * 16 + lg * 4 + r;
      long rq = trow(q);
      float ri = rinv[mi][r];
#pragma unroll
      for (int ni = 0; ni < 2; ++ni)
        y[rq * 192 + h * 32 + ni * 16 + lr] = f2bf(o[mi][ni][r] * ri);
    }
  }
}

// ---------- depthwise 3x3 conv + GELU on one 128-row chunk ----------
// hbc: [130 slots][256][768] bf16, slot j = global y (yh*128 - 1 + j)
// h2c: [128][256][768] bf16, rows y = yh*128 + py
__global__ __launch_bounds__(256) void dwconv_kernel(const short* __restrict__ hbc,
                                                     const float* __restrict__ dww,
                                                     const float* __restrict__ dwb,
                                                     short* __restrict__ h2c,
                                                     int yh) {
  long t = (long)blockIdx.x * 256 + threadIdx.x;  // 128*256*96 = 3,145,728
  int cg = (int)(t % 96);
  int px = (int)((t / 96) % 256);
  int py = (int)(t / 24576);  // 0..127
  int ybase = yh * 128 + py;
  float acc[8] = {0, 0, 0, 0, 0, 0, 0, 0};
#pragma unroll
  for (int dy = 0; dy < 3; ++dy) {
    int yy = ybase + dy - 1;
    if (yy < 0 || yy > 255) continue;
    int slot = py + dy;  // yy - (yh*128 - 1)
#pragma unroll
    for (int dx = 0; dx < 3; ++dx) {
      int xx = px + dx - 1;
      if (xx < 0 || xx > 255) continue;
      long base = ((long)slot * 256 + xx) * 768 + cg * 8;
      bf16x8 hv = *(const bf16x8*)(hbc + base);
#pragma unroll
      for (int j = 0; j < 8; ++j)
        acc[j] += bf2f(hv[j]) * dww[(dy * 3 + dx) * 768 + cg * 8 + j];
    }
  }
  bf16x8 ov;
#pragma unroll
  for (int j = 0; j < 8; ++j) ov[j] = f2bf(gelu_exact(acc[j] + dwb[cg * 8 + j]));
  *(bf16x8*)(h2c + t * 8) = ov;
}

// ---------- launch ----------
extern "C" void kernel_launch(void* const* d_in, const int* in_sizes, int n_in,
                              void* d_out, int out_size, void* d_ws, size_t ws_size,
                              hipStream_t stream) {
  const float* x = (const float*)d_in[0];
  const float* n1w = (const float*)d_in[1];
  const float* n1b = (const float*)d_in[2];
  const float* q_w = (const float*)d_in[3];
  const float* q_b = (const float*)d_in[4];
  const float* kv_w = (const float*)d_in[5];
  const float* kv_b = (const float*)d_in[6];
  const float* rpb = (const float*)d_in[7];
  const float* proj_w = (const float*)d_in[8];
  const float* proj_b = (const float*)d_in[9];
  const float* n2w = (const float*)d_in[10];
  const float* n2b = (const float*)d_in[11];
  const float* l1_w = (const float*)d_in[12];
  const float* l1_b = (const float*)d_in[13];
  const float* dw_w = (const float*)d_in[14];
  const float* dw_b = (const float*)d_in[15];
  const float* l2_w = (const float*)d_in[16];
  const float* l2_b = (const float*)d_in[17];
  float* out = (float*)d_out;

  // ---- workspace layout, total 253,329,408 B ----
  char* ws = (char*)d_ws;
  short* xn = (short*)ws;                    // [0, 48M): xn -> yb -> xn2
  short* qkv = (short*)(ws + 50331648);      // [48M, 192M): dead after attn
  float* x2 = (float*)(ws + 50331648);       // [48M, 144M): after qkv dead
  short* hbc = (short*)(ws + 150994944);     // 130*256*768*2 = 51,118,080
  short* h2c = (short*)(ws + 202113024);     // 128*256*768*2 = 50,331,648
  short* bt1 = (short*)(ws + 252444672);     // [576][192]
  short* bt2 = bt1 + 110592;                 // [192][192]
  short* bt3 = bt2 + 36864;                  // [768][192]
  short* bt4 = bt3 + 147456;                 // [192][768] ends 253,329,408
  short* yb = xn;   // attn output reuses xn region (xn dead after qkv gemm)
  short* xn2 = xn;  // ln2 output reuses again (yb dead after proj)

  // pre-transpose weights to bf16 [N][K]
  wprep_kernel<<<144, 256, 0, stream>>>(q_w, bt1, 192, 192);
  wprep_kernel<<<288, 256, 0, stream>>>(kv_w, bt1 + 36864, 192, 384);
  wprep_kernel<<<144, 256, 0, stream>>>(proj_w, bt2, 192, 192);
  wprep_kernel<<<576, 256, 0, stream>>>(l1_w, bt3, 192, 768);
  wprep_kernel<<<576, 256, 0, stream>>>(l2_w, bt4, 768, 192);

  ln_kernel<<<32768, 256, 0, stream>>>(x, n1w, n1b, xn);
  gemm_kernel<128, 192, 576, 0><<<1024, 256, 0, stream>>>(
      xn, bt1, q_b, kv_b, nullptr, qkv);
  attn_kernel<<<12288, 64, 0, stream>>>(qkv, rpb, yb);
  gemm_kernel<128, 192, 192, 1><<<1024, 256, 0, stream>>>(
      yb, bt2, proj_b, nullptr, x, x2);
  ln_kernel<<<32768, 256, 0, stream>>>(x2, n2w, n2b, xn2);

  // LeFF in 4 chunks: (batch b, y-half yh), 129 rows w/ 1-row conv halo
  for (int c = 0; c < 4; ++c) {
    int b = c >> 1, yh = c & 1;
    int ystart = yh ? 127 : 0;   // first y row computed by l1 (129 rows)
    int s0 = yh ? 0 : 1;         // hbc slot of ystart
    long tok0 = (long)b * 65536 + (long)ystart * 256;        // l1 input rows
    long ooff = ((long)b * 65536 + (long)yh * 32768) * 192;  // output offset
    gemm_kernel<64, 192, 768, 2><<<516, 256, 0, stream>>>(
        xn2 + tok0 * 192, bt3, l1_b, nullptr, nullptr, hbc + (long)s0 * 196608);
    dwconv_kernel<<<12288, 256, 0, stream>>>(hbc, dw_w, dw_b, h2c, yh);
    gemm_kernel<64, 768, 192, 1><<<512, 256, 0, stream>>>(
        h2c, bt4, l2_b, nullptr, x2 + ooff, out + ooff);
  }
}

// Round 4
// 939.071 us; speedup vs baseline: 1.4921x; 1.4921x over previous
//
#include <hip/hip_runtime.h>
#include <math.h>

typedef float f32x4 __attribute__((ext_vector_type(4)));
typedef short bf16x8 __attribute__((ext_vector_type(8)));

__device__ __forceinline__ short f2bf(float f) {
  unsigned u = __builtin_bit_cast(unsigned, f);
  u = (u + 0x7FFFu + ((u >> 16) & 1u)) >> 16;
  return (short)u;
}
__device__ __forceinline__ float bf2f(short s) {
  unsigned u = ((unsigned)(unsigned short)s) << 16;
  return __builtin_bit_cast(float, u);
}
__device__ __forceinline__ float gelu_exact(float x) {
  return 0.5f * x * (1.0f + erff(x * 0.70710678118654752f));
}

// window-order row for original pixel row (b, ho, wo): shift by -4 then partition
__device__ __forceinline__ long perm_row(int b, int ho, int wo) {
  int hs = (ho + 252) & 255, ws = (wo + 252) & 255;
  int w = ((hs >> 3) << 5) | (ws >> 3);
  int t = ((hs & 7) << 3) | (ws & 7);
  return ((long)b << 16) | (w << 6) | t;
}
// inverse: window-order row -> original row
__device__ __forceinline__ long unperm_row(long m) {
  int b = (int)(m >> 16);
  int w = ((int)m >> 6) & 1023, t = (int)m & 63;
  int hs = ((w >> 5) << 3) | (t >> 3);
  int ws = ((w & 31) << 3) | (t & 7);
  int ho = (hs + 4) & 255, wo = (ws + 4) & 255;
  return ((long)b << 16) | (ho << 8) | wo;
}

// ---------- LN1: fp32 token-order in -> bf16 window-order out ----------
__global__ __launch_bounds__(256) void ln1_kernel(const float* __restrict__ x,
                                                  const float* __restrict__ w,
                                                  const float* __restrict__ b,
                                                  short* __restrict__ out) {
  int lane = threadIdx.x & 63;
  long row = (long)blockIdx.x * 4 + (threadIdx.x >> 6);
  const float* xr = x + row * 192;
  float v0 = xr[lane], v1 = xr[lane + 64], v2 = xr[lane + 128];
  float s = v0 + v1 + v2, s2 = v0 * v0 + v1 * v1 + v2 * v2;
#pragma unroll
  for (int m = 1; m < 64; m <<= 1) {
    s += __shfl_xor(s, m);
    s2 += __shfl_xor(s2, m);
  }
  float mu = s * (1.0f / 192.0f);
  float rstd = rsqrtf(s2 * (1.0f / 192.0f) - mu * mu + 1e-5f);
  long drow = perm_row((int)(row >> 16), ((int)row >> 8) & 255, (int)row & 255);
  short* o = out + drow * 192;
  o[lane] = f2bf((v0 - mu) * rstd * w[lane] + b[lane]);
  o[lane + 64] = f2bf((v1 - mu) * rstd * w[lane + 64] + b[lane + 64]);
  o[lane + 128] = f2bf((v2 - mu) * rstd * w[lane + 128] + b[lane + 128]);
}

// ---------- LN2: bf16 token-order in -> bf16 token-order out ----------
__global__ __launch_bounds__(256) void ln2_kernel(const short* __restrict__ x,
                                                  const float* __restrict__ w,
                                                  const float* __restrict__ b,
                                                  short* __restrict__ out) {
  int lane = threadIdx.x & 63;
  long row = (long)blockIdx.x * 4 + (threadIdx.x >> 6);
  const short* xr = x + row * 192;
  float v0 = bf2f(xr[lane]), v1 = bf2f(xr[lane + 64]), v2 = bf2f(xr[lane + 128]);
  float s = v0 + v1 + v2, s2 = v0 * v0 + v1 * v1 + v2 * v2;
#pragma unroll
  for (int m = 1; m < 64; m <<= 1) {
    s += __shfl_xor(s, m);
    s2 += __shfl_xor(s2, m);
  }
  float mu = s * (1.0f / 192.0f);
  float rstd = rsqrtf(s2 * (1.0f / 192.0f) - mu * mu + 1e-5f);
  short* o = out + row * 192;
  o[lane] = f2bf((v0 - mu) * rstd * w[lane] + b[lane]);
  o[lane + 64] = f2bf((v1 - mu) * rstd * w[lane + 64] + b[lane + 64]);
  o[lane + 128] = f2bf((v2 - mu) * rstd * w[lane + 128] + b[lane + 128]);
}

// ---------- weight prep: W[K][N] fp32 -> Bt[N][K] bf16 ----------
__global__ __launch_bounds__(256) void wprep_kernel(const float* __restrict__ w,
                                                    short* __restrict__ bt,
                                                    int K, int N) {
  long i = (long)blockIdx.x * 256 + threadIdx.x;
  if (i >= (long)K * N) return;
  int n = (int)(i / K), k = (int)(i % K);
  bt[i] = f2bf(w[(long)k * N + n]);
}

// ---------- GEMM (K=192): B in regs, in-kernel m-loop, XCD-exact mapping ----
// EPI 0: + bias(B0 col<192 / B1 col>=192)       -> bf16  (qkv, window order)
// EPI 2: gelu(+ bias)                            -> bf16  (l1)
// EPI 3: + bias + resid fp32 @unperm row, unperm -> bf16  (proj)
template <int NTOT, int EPI>
__global__ __launch_bounds__(256) void gemm1_kernel(
    const short* __restrict__ A, const short* __restrict__ Bt,
    const float* __restrict__ B0, const float* __restrict__ B1,
    const float* __restrict__ residf, short* __restrict__ outp,
    int nblk, int mgx, int iters, int mtiles) {
  __shared__ short As[128][200];
  const int tid = threadIdx.x;
  const int lane = tid & 63, wid = tid >> 6;
  const int lr = lane & 15, lg = lane >> 4;
  const int xcd = blockIdx.x & 7;
  const int i = blockIdx.x >> 3;
  const int n0 = (i % nblk) * 64;
  const int mg = xcd * mgx + i / nblk;

  bf16x8 bf[6][4];
#pragma unroll
  for (int ks = 0; ks < 6; ++ks)
#pragma unroll
    for (int ni = 0; ni < 4; ++ni)
      bf[ks][ni] = *(const bf16x8*)(Bt + (long)(n0 + ni * 16 + lr) * 192 +
                                    ks * 32 + lg * 8);

#pragma unroll 1
  for (int it = 0; it < iters; ++it) {
    int mt = mg * iters + it;
    if (mt >= mtiles) continue;  // block-uniform
    long m0 = (long)mt * 128;
    __syncthreads();
#pragma unroll
    for (int p = 0; p < 12; ++p) {
      int ci = tid + p * 256;
      int r = ci / 24, c = ci % 24;
      *(float4*)(&As[r][c * 8]) = *(const float4*)(A + (m0 + r) * 192 + c * 8);
    }
    __syncthreads();
    f32x4 acc[2][4] = {};
#pragma unroll
    for (int ks = 0; ks < 6; ++ks) {
      bf16x8 a0 = *(const bf16x8*)(&As[wid * 32 + lr][ks * 32 + lg * 8]);
      bf16x8 a1 = *(const bf16x8*)(&As[wid * 32 + 16 + lr][ks * 32 + lg * 8]);
#pragma unroll
      for (int ni = 0; ni < 4; ++ni) {
        acc[0][ni] = __builtin_amdgcn_mfma_f32_16x16x32_bf16(a0, bf[ks][ni],
                                                             acc[0][ni], 0, 0, 0);
        acc[1][ni] = __builtin_amdgcn_mfma_f32_16x16x32_bf16(a1, bf[ks][ni],
                                                             acc[1][ni], 0, 0, 0);
      }
    }
    // epilogue: C layout col=lane&15, row=(lane>>4)*4+reg
#pragma unroll
    for (int mi = 0; mi < 2; ++mi) {
#pragma unroll
      for (int ni = 0; ni < 4; ++ni) {
        int n = n0 + ni * 16 + lr;
        long rowb = m0 + wid * 32 + mi * 16 + lg * 4;
#pragma unroll
        for (int r = 0; r < 4; ++r) {
          float v = acc[mi][ni][r];
          long m = rowb + r;
          if constexpr (EPI == 0) {
            float bb = (n < 192) ? B0[n] : B1[n - 192];
            outp[m * NTOT + n] = f2bf(v + bb);
          } else if constexpr (EPI == 2) {
            outp[m * NTOT + n] = f2bf(gelu_exact(v + B0[n]));
          } else {
            long oidx = unperm_row(m) * 192 + n;
            outp[oidx] = f2bf(v + B0[n] + residf[oidx]);
          }
        }
      }
    }
  }
}

// ---------- GEMM K=768 (l2): A+B staged in LDS, BM=128 x BN=192 ----------
__global__ __launch_bounds__(256) void gemm2_kernel(
    const short* __restrict__ A, const short* __restrict__ Bt,
    const float* __restrict__ bias, const short* __restrict__ residb,
    float* __restrict__ outp) {
  __shared__ short As[128][72];
  __shared__ short Bs[192][72];
  const int tid = threadIdx.x;
  const int lane = tid & 63, wid = tid >> 6;
  const int lr = lane & 15, lg = lane >> 4;
  const int wm = wid >> 1, wn = wid & 1;  // 2x2 waves: 64 rows x 96 cols each
  const long m0 = (long)blockIdx.x * 128;

  f32x4 acc[4][6] = {};
#pragma unroll 1
  for (int kc = 0; kc < 12; ++kc) {
    __syncthreads();
#pragma unroll
    for (int p = 0; p < 4; ++p) {  // A: 128x64 = 1024 chunks
      int g = p * 256 + tid;
      int r = g >> 3, c = g & 7;
      *(float4*)(&As[r][c * 8]) =
          *(const float4*)(A + (m0 + r) * 768 + kc * 64 + c * 8);
    }
#pragma unroll
    for (int p = 0; p < 6; ++p) {  // B: 192x64 = 1536 chunks
      int g = p * 256 + tid;
      int n = g >> 3, c = g & 7;
      *(float4*)(&Bs[n][c * 8]) =
          *(const float4*)(Bt + (long)n * 768 + kc * 64 + c * 8);
    }
    __syncthreads();
#pragma unroll
    for (int ks = 0; ks < 2; ++ks) {
      bf16x8 a[4], b[6];
#pragma unroll
      for (int mf = 0; mf < 4; ++mf)
        a[mf] = *(const bf16x8*)(&As[wm * 64 + mf * 16 + lr][ks * 32 + lg * 8]);
#pragma unroll
      for (int nf = 0; nf < 6; ++nf)
        b[nf] = *(const bf16x8*)(&Bs[wn * 96 + nf * 16 + lr][ks * 32 + lg * 8]);
#pragma unroll
      for (int mf = 0; mf < 4; ++mf)
#pragma unroll
        for (int nf = 0; nf < 6; ++nf)
          acc[mf][nf] = __builtin_amdgcn_mfma_f32_16x16x32_bf16(
              a[mf], b[nf], acc[mf][nf], 0, 0, 0);
    }
  }
#pragma unroll
  for (int mf = 0; mf < 4; ++mf)
#pragma unroll
    for (int nf = 0; nf < 6; ++nf) {
      int n = wn * 96 + nf * 16 + lr;
      long rowb = m0 + wm * 64 + mf * 16 + lg * 4;
#pragma unroll
      for (int r = 0; r < 4; ++r) {
        long idx = (rowb + r) * 192 + n;
        outp[idx] = acc[mf][nf][r] + bias[n] + bf2f(residb[idx]);
      }
    }
}

// ---------- windowed attention: one wave per (window, head); linear IO ----
__global__ __launch_bounds__(64) void attn_kernel(const short* __restrict__ qkv,
                                                  const float* __restrict__ rpb,
                                                  short* __restrict__ y) {
  __shared__ short vT[32][72];  // [d][token]
  __shared__ short P[64][72];   // [q][k]
  const int lane = threadIdx.x;
  const int bid = blockIdx.x;
  const int h = bid % 6;
  const long wglob = bid / 6;        // b*1024 + w
  const int w = (int)wglob & 1023;
  const int wr = w >> 5, wc = w & 31;
  const long wbase = wglob * 64;
  const int lr = lane & 15, lg = lane >> 4;

  bf16x8 aq[4], bk[4];
#pragma unroll
  for (int i = 0; i < 4; ++i) {
    long rq = wbase + i * 16 + lr;
    aq[i] = *(const bf16x8*)(qkv + rq * 576 + h * 32 + lg * 8);
    bk[i] = *(const bf16x8*)(qkv + rq * 576 + 192 + h * 32 + lg * 8);
  }
  {  // stage V transposed: vT[d][token]
    const short* vp = qkv + (wbase + lane) * 576 + 384 + h * 32;
#pragma unroll
    for (int q4 = 0; q4 < 4; ++q4) {
      bf16x8 vv = *(const bf16x8*)(vp + q4 * 8);
#pragma unroll
      for (int j = 0; j < 8; ++j) vT[q4 * 8 + j][lane] = vv[j];
    }
  }

  f32x4 s[4][4] = {};
#pragma unroll
  for (int mi = 0; mi < 4; ++mi)
#pragma unroll
    for (int ni = 0; ni < 4; ++ni)
      s[mi][ni] = __builtin_amdgcn_mfma_f32_16x16x32_bf16(aq[mi], bk[ni],
                                                          s[mi][ni], 0, 0, 0);

  const float SCALE = 0.17677669529663687f;
  float rinv[4][4];
#pragma unroll
  for (int mi = 0; mi < 4; ++mi) {
#pragma unroll
    for (int r = 0; r < 4; ++r) {
      int q = mi * 16 + lg * 4 + r;
      int qh = wr * 8 + (q >> 3), qw = wc * 8 + (q & 7);  // shifted coords
      int ridq = 3 * ((qh < 248) ? 0 : ((qh < 252) ? 1 : 2)) +
                 ((qw < 248) ? 0 : ((qw < 252) ? 1 : 2));
      float lv[4];
      float mx = -1e30f;
#pragma unroll
      for (int ni = 0; ni < 4; ++ni) {
        int k = ni * 16 + lr;
        int dr = (q >> 3) - (k >> 3) + 7;
        int dc = (q & 7) - (k & 7) + 7;
        float bias = rpb[(dr * 15 + dc) * 6 + h];
        int kh = wr * 8 + (k >> 3), kw = wc * 8 + (k & 7);
        int ridk = 3 * ((kh < 248) ? 0 : ((kh < 252) ? 1 : 2)) +
                   ((kw < 248) ? 0 : ((kw < 252) ? 1 : 2));
        float lvv = s[mi][ni][r] * SCALE + bias + ((ridq != ridk) ? -100.0f : 0.0f);
        lv[ni] = lvv;
        mx = fmaxf(mx, lvv);
      }
#pragma unroll
      for (int m = 1; m < 16; m <<= 1) mx = fmaxf(mx, __shfl_xor(mx, m));
      float sum = 0.0f;
#pragma unroll
      for (int ni = 0; ni < 4; ++ni) {
        float p = expf(lv[ni] - mx);
        lv[ni] = p;
        sum += p;
      }
#pragma unroll
      for (int m = 1; m < 16; m <<= 1) sum += __shfl_xor(sum, m);
      rinv[mi][r] = 1.0f / sum;
#pragma unroll
      for (int ni = 0; ni < 4; ++ni) P[q][ni * 16 + lr] = f2bf(lv[ni]);
    }
  }
  __syncthreads();

  f32x4 o[4][2] = {};
#pragma unroll
  for (int ks = 0; ks < 2; ++ks) {
    bf16x8 ap[4], bv[2];
#pragma unroll
    for (int mi = 0; mi < 4; ++mi)
      ap[mi] = *(const bf16x8*)(&P[mi * 16 + lr][ks * 32 + lg * 8]);
#pragma unroll
    for (int ni = 0; ni < 2; ++ni)
      bv[ni] = *(const bf16x8*)(&vT[ni * 16 + lr][ks * 32 + lg * 8]);
#pragma unroll
    for (int mi = 0; mi < 4; ++mi)
#pragma unroll
      for (int ni = 0; ni < 2; ++ni)
        o[mi][ni] = __builtin_amdgcn_mfma_f32_16x16x32_bf16(ap[mi], bv[ni],
                                                            o[mi][ni], 0, 0, 0);
  }
#pragma unroll
  for (int mi = 0; mi < 4; ++mi) {
#pragma unroll
    for (int r = 0; r < 4; ++r) {
      int q = mi * 16 + lg * 4 + r;
      float ri = rinv[mi][r];
#pragma unroll
      for (int ni = 0; ni < 2; ++ni)
        y[(wbase + q) * 192 + h * 32 + ni * 16 + lr] = f2bf(o[mi][ni][r] * ri);
    }
  }
}

// ---------- depthwise 3x3 conv + GELU on one 128-row chunk ----------
__global__ __launch_bounds__(256) void dwconv_kernel(const short* __restrict__ hbc,
                                                     const float* __restrict__ dww,
                                                     const float* __restrict__ dwb,
                                                     short* __restrict__ h2c,
                                                     int yh) {
  long t = (long)blockIdx.x * 256 + threadIdx.x;  // 3,145,728 threads
  int cg = (int)(t % 96);
  int px = (int)((t / 96) % 256);
  int py = (int)(t / 24576);
  int ybase = yh * 128 + py;
  float acc[8] = {0, 0, 0, 0, 0, 0, 0, 0};
#pragma unroll
  for (int dy = 0; dy < 3; ++dy) {
    int yy = ybase + dy - 1;
    if (yy < 0 || yy > 255) continue;
    int slot = py + dy;
#pragma unroll
    for (int dx = 0; dx < 3; ++dx) {
      int xx = px + dx - 1;
      if (xx < 0 || xx > 255) continue;
      long base = ((long)slot * 256 + xx) * 768 + cg * 8;
      bf16x8 hv = *(const bf16x8*)(hbc + base);
#pragma unroll
      for (int j = 0; j < 8; ++j)
        acc[j] += bf2f(hv[j]) * dww[(dy * 3 + dx) * 768 + cg * 8 + j];
    }
  }
  bf16x8 ov;
#pragma unroll
  for (int j = 0; j < 8; ++j) ov[j] = f2bf(gelu_exact(acc[j] + dwb[cg * 8 + j]));
  *(bf16x8*)(h2c + t * 8) = ov;
}

// ---------- launch ----------
extern "C" void kernel_launch(void* const* d_in, const int* in_sizes, int n_in,
                              void* d_out, int out_size, void* d_ws, size_t ws_size,
                              hipStream_t stream) {
  const float* x = (const float*)d_in[0];
  const float* n1w = (const float*)d_in[1];
  const float* n1b = (const float*)d_in[2];
  const float* q_w = (const float*)d_in[3];
  const float* q_b = (const float*)d_in[4];
  const float* kv_w = (const float*)d_in[5];
  const float* kv_b = (const float*)d_in[6];
  const float* rpb = (const float*)d_in[7];
  const float* proj_w = (const float*)d_in[8];
  const float* proj_b = (const float*)d_in[9];
  const float* n2w = (const float*)d_in[10];
  const float* n2b = (const float*)d_in[11];
  const float* l1_w = (const float*)d_in[12];
  const float* l1_b = (const float*)d_in[13];
  const float* dw_w = (const float*)d_in[14];
  const float* dw_b = (const float*)d_in[15];
  const float* l2_w = (const float*)d_in[16];
  const float* l2_b = (const float*)d_in[17];
  float* out = (float*)d_out;

  // ---- workspace: total ~252.5 MB ----
  char* ws = (char*)d_ws;
  short* xn = (short*)ws;                     // [0,48M): xn(win) -> yb -> xn2
  short* qkv = (short*)(ws + 50331648);       // [48M,192M) window order
  short* hbc = (short*)(ws + 50331648);       // reuse: 51,118,080 B
  short* h2c = (short*)(ws + 101449728);      // 50,331,648 B (ends 144.7M)
  short* x2bf = (short*)(ws + 201326592);     // [192M,240M) token order bf16
  short* bt1 = (short*)(ws + 251658240);      // [576][192]
  short* bt2 = bt1 + 110592;                  // [192][192]
  short* bt3 = bt2 + 36864;                   // [768][192]
  short* bt4 = bt3 + 147456;                  // [192][768]
  short* yb = xn;
  short* xn2 = xn;

  wprep_kernel<<<144, 256, 0, stream>>>(q_w, bt1, 192, 192);
  wprep_kernel<<<288, 256, 0, stream>>>(kv_w, bt1 + 36864, 192, 384);
  wprep_kernel<<<144, 256, 0, stream>>>(proj_w, bt2, 192, 192);
  wprep_kernel<<<576, 256, 0, stream>>>(l1_w, bt3, 192, 768);
  wprep_kernel<<<576, 256, 0, stream>>>(l2_w, bt4, 768, 192);

  ln1_kernel<<<32768, 256, 0, stream>>>(x, n1w, n1b, xn);
  // qkv: 1024 m-tiles, 9 n-blocks; grid 8 xcd * 16 mg * 9 n = 1152
  gemm1_kernel<576, 0><<<1152, 256, 0, stream>>>(xn, bt1, q_b, kv_b, nullptr,
                                                 qkv, 9, 16, 8, 1024);
  attn_kernel<<<12288, 64, 0, stream>>>(qkv, rpb, yb);
  // proj: 1024 m-tiles, 3 n-blocks; grid 8*16*3 = 384; unperm + resid(x fp32)
  gemm1_kernel<192, 3><<<384, 256, 0, stream>>>(yb, bt2, proj_b, nullptr, x,
                                                x2bf, 3, 16, 8, 1024);
  ln2_kernel<<<32768, 256, 0, stream>>>(x2bf, n2w, n2b, xn2);

  // LeFF in 4 chunks: (batch b, y-half yh), 129 rows with 1-row conv halo
  for (int c = 0; c < 4; ++c) {
    int b = c >> 1, yh = c & 1;
    int ystart = yh ? 127 : 0;
    int s0 = yh ? 0 : 1;
    long tok0 = (long)b * 65536 + (long)ystart * 256;
    long ooff = ((long)b * 65536 + (long)yh * 32768) * 192;
    // l1: 258 m-tiles, 12 n-blocks; grid 8*6*12 = 576 (tail-guarded)
    gemm1_kernel<768, 2><<<576, 256, 0, stream>>>(
        xn2 + tok0 * 192, bt3, l1_b, nullptr, nullptr,
        hbc + (long)s0 * 196608, 12, 6, 6, 258);
    dwconv_kernel<<<12288, 256, 0, stream>>>(hbc, dw_w, dw_b, h2c, yh);
    // l2: 256 m-tiles, full N=192 per block
    gemm2_kernel<<<256, 256, 0, stream>>>(h2c, bt4, l2_b, x2bf + ooff,
                                          out + ooff);
  }
}

// Round 5
// 845.806 us; speedup vs baseline: 1.6566x; 1.1103x over previous
//
#include <hip/hip_runtime.h>
#include <math.h>

typedef float f32x4 __attribute__((ext_vector_type(4)));
typedef short bf16x8 __attribute__((ext_vector_type(8)));

__device__ __forceinline__ short f2bf(float f) {
  unsigned u = __builtin_bit_cast(unsigned, f);
  u = (u + 0x7FFFu + ((u >> 16) & 1u)) >> 16;
  return (short)u;
}
__device__ __forceinline__ float bf2f(short s) {
  unsigned u = ((unsigned)(unsigned short)s) << 16;
  return __builtin_bit_cast(float, u);
}
__device__ __forceinline__ float gelu_exact(float x) {
  return 0.5f * x * (1.0f + erff(x * 0.70710678118654752f));
}

// window-order row for original pixel row (b, ho, wo): shift by -4 then partition
__device__ __forceinline__ long perm_row(int b, int ho, int wo) {
  int hs = (ho + 252) & 255, ws = (wo + 252) & 255;
  int w = ((hs >> 3) << 5) | (ws >> 3);
  int t = ((hs & 7) << 3) | (ws & 7);
  return ((long)b << 16) | (w << 6) | t;
}
// inverse: window-order row -> original row
__device__ __forceinline__ long unperm_row(long m) {
  int b = (int)(m >> 16);
  int w = ((int)m >> 6) & 1023, t = (int)m & 63;
  int hs = ((w >> 5) << 3) | (t >> 3);
  int ws = ((w & 31) << 3) | (t & 7);
  int ho = (hs + 4) & 255, wo = (ws + 4) & 255;
  return ((long)b << 16) | (ho << 8) | wo;
}

// ---------- LN1: fp32 token-order in -> bf16 window-order out ----------
__global__ __launch_bounds__(256) void ln1_kernel(const float* __restrict__ x,
                                                  const float* __restrict__ w,
                                                  const float* __restrict__ b,
                                                  short* __restrict__ out) {
  int lane = threadIdx.x & 63;
  long row = (long)blockIdx.x * 4 + (threadIdx.x >> 6);
  const float* xr = x + row * 192;
  float v0 = xr[lane], v1 = xr[lane + 64], v2 = xr[lane + 128];
  float s = v0 + v1 + v2, s2 = v0 * v0 + v1 * v1 + v2 * v2;
#pragma unroll
  for (int m = 1; m < 64; m <<= 1) {
    s += __shfl_xor(s, m);
    s2 += __shfl_xor(s2, m);
  }
  float mu = s * (1.0f / 192.0f);
  float rstd = rsqrtf(s2 * (1.0f / 192.0f) - mu * mu + 1e-5f);
  long drow = perm_row((int)(row >> 16), ((int)row >> 8) & 255, (int)row & 255);
  short* o = out + drow * 192;
  o[lane] = f2bf((v0 - mu) * rstd * w[lane] + b[lane]);
  o[lane + 64] = f2bf((v1 - mu) * rstd * w[lane + 64] + b[lane + 64]);
  o[lane + 128] = f2bf((v2 - mu) * rstd * w[lane + 128] + b[lane + 128]);
}

// ---------- LN2: bf16 token-order in -> bf16 token-order out ----------
__global__ __launch_bounds__(256) void ln2_kernel(const short* __restrict__ x,
                                                  const float* __restrict__ w,
                                                  const float* __restrict__ b,
                                                  short* __restrict__ out) {
  int lane = threadIdx.x & 63;
  long row = (long)blockIdx.x * 4 + (threadIdx.x >> 6);
  const short* xr = x + row * 192;
  float v0 = bf2f(xr[lane]), v1 = bf2f(xr[lane + 64]), v2 = bf2f(xr[lane + 128]);
  float s = v0 + v1 + v2, s2 = v0 * v0 + v1 * v1 + v2 * v2;
#pragma unroll
  for (int m = 1; m < 64; m <<= 1) {
    s += __shfl_xor(s, m);
    s2 += __shfl_xor(s2, m);
  }
  float mu = s * (1.0f / 192.0f);
  float rstd = rsqrtf(s2 * (1.0f / 192.0f) - mu * mu + 1e-5f);
  short* o = out + row * 192;
  o[lane] = f2bf((v0 - mu) * rstd * w[lane] + b[lane]);
  o[lane + 64] = f2bf((v1 - mu) * rstd * w[lane + 64] + b[lane + 64]);
  o[lane + 128] = f2bf((v2 - mu) * rstd * w[lane + 128] + b[lane + 128]);
}

// ---------- weight prep: W[K][N] fp32 -> Bt[N][K] bf16 ----------
__global__ __launch_bounds__(256) void wprep_kernel(const float* __restrict__ w,
                                                    short* __restrict__ bt,
                                                    int K, int N) {
  long i = (long)blockIdx.x * 256 + threadIdx.x;
  if (i >= (long)K * N) return;
  int n = (int)(i / K), k = (int)(i % K);
  bt[i] = f2bf(w[(long)k * N + n]);
}

// ---------- GEMM (K=192): B in regs, in-kernel m-loop, XCD-exact mapping ----
// EPI 0: + bias(B0 col<192 / B1 col>=192)       -> bf16  (qkv, window order)
// EPI 2: gelu(+ bias)                            -> bf16  (l1)
// EPI 3: + bias + resid fp32 @unperm row, unperm -> bf16  (proj)
template <int NTOT, int EPI>
__global__ __launch_bounds__(256) void gemm1_kernel(
    const short* __restrict__ A, const short* __restrict__ Bt,
    const float* __restrict__ B0, const float* __restrict__ B1,
    const float* __restrict__ residf, short* __restrict__ outp,
    int nblk, int mgx, int iters, int mtiles) {
  __shared__ short As[128][200];
  const int tid = threadIdx.x;
  const int lane = tid & 63, wid = tid >> 6;
  const int lr = lane & 15, lg = lane >> 4;
  const int xcd = blockIdx.x & 7;
  const int i = blockIdx.x >> 3;
  const int n0 = (i % nblk) * 64;
  const int mg = xcd * mgx + i / nblk;

  bf16x8 bf[6][4];
#pragma unroll
  for (int ks = 0; ks < 6; ++ks)
#pragma unroll
    for (int ni = 0; ni < 4; ++ni)
      bf[ks][ni] = *(const bf16x8*)(Bt + (long)(n0 + ni * 16 + lr) * 192 +
                                    ks * 32 + lg * 8);

#pragma unroll 1
  for (int it = 0; it < iters; ++it) {
    int mt = mg * iters + it;
    if (mt >= mtiles) continue;  // block-uniform
    long m0 = (long)mt * 128;
    __syncthreads();
#pragma unroll
    for (int p = 0; p < 12; ++p) {
      int ci = tid + p * 256;
      int r = ci / 24, c = ci % 24;
      *(float4*)(&As[r][c * 8]) = *(const float4*)(A + (m0 + r) * 192 + c * 8);
    }
    __syncthreads();
    f32x4 acc[2][4] = {};
#pragma unroll
    for (int ks = 0; ks < 6; ++ks) {
      bf16x8 a0 = *(const bf16x8*)(&As[wid * 32 + lr][ks * 32 + lg * 8]);
      bf16x8 a1 = *(const bf16x8*)(&As[wid * 32 + 16 + lr][ks * 32 + lg * 8]);
#pragma unroll
      for (int ni = 0; ni < 4; ++ni) {
        acc[0][ni] = __builtin_amdgcn_mfma_f32_16x16x32_bf16(a0, bf[ks][ni],
                                                             acc[0][ni], 0, 0, 0);
        acc[1][ni] = __builtin_amdgcn_mfma_f32_16x16x32_bf16(a1, bf[ks][ni],
                                                             acc[1][ni], 0, 0, 0);
      }
    }
    // epilogue: C layout col=lane&15, row=(lane>>4)*4+reg
#pragma unroll
    for (int mi = 0; mi < 2; ++mi) {
#pragma unroll
      for (int ni = 0; ni < 4; ++ni) {
        int n = n0 + ni * 16 + lr;
        long rowb = m0 + wid * 32 + mi * 16 + lg * 4;
#pragma unroll
        for (int r = 0; r < 4; ++r) {
          float v = acc[mi][ni][r];
          long m = rowb + r;
          if constexpr (EPI == 0) {
            float bb = (n < 192) ? B0[n] : B1[n - 192];
            outp[m * NTOT + n] = f2bf(v + bb);
          } else if constexpr (EPI == 2) {
            outp[m * NTOT + n] = f2bf(gelu_exact(v + B0[n]));
          } else {
            long oidx = unperm_row(m) * 192 + n;
            outp[oidx] = f2bf(v + B0[n] + residf[oidx]);
          }
        }
      }
    }
  }
}

// ---------- GEMM K=768 (l2): A+B staged in LDS, BM=128 x BN=192 ----------
__global__ __launch_bounds__(256) void gemm2_kernel(
    const short* __restrict__ A, const short* __restrict__ Bt,
    const float* __restrict__ bias, const short* __restrict__ residb,
    float* __restrict__ outp) {
  __shared__ short As[128][72];
  __shared__ short Bs[192][72];
  const int tid = threadIdx.x;
  const int lane = tid & 63, wid = tid >> 6;
  const int lr = lane & 15, lg = lane >> 4;
  const int wm = wid >> 1, wn = wid & 1;  // 2x2 waves: 64 rows x 96 cols each
  const long m0 = (long)blockIdx.x * 128;

  f32x4 acc[4][6] = {};
#pragma unroll 1
  for (int kc = 0; kc < 12; ++kc) {
    __syncthreads();
#pragma unroll
    for (int p = 0; p < 4; ++p) {  // A: 128x64 = 1024 chunks
      int g = p * 256 + tid;
      int r = g >> 3, c = g & 7;
      *(float4*)(&As[r][c * 8]) =
          *(const float4*)(A + (m0 + r) * 768 + kc * 64 + c * 8);
    }
#pragma unroll
    for (int p = 0; p < 6; ++p) {  // B: 192x64 = 1536 chunks
      int g = p * 256 + tid;
      int n = g >> 3, c = g & 7;
      *(float4*)(&Bs[n][c * 8]) =
          *(const float4*)(Bt + (long)n * 768 + kc * 64 + c * 8);
    }
    __syncthreads();
#pragma unroll
    for (int ks = 0; ks < 2; ++ks) {
      bf16x8 a[4], b[6];
#pragma unroll
      for (int mf = 0; mf < 4; ++mf)
        a[mf] = *(const bf16x8*)(&As[wm * 64 + mf * 16 + lr][ks * 32 + lg * 8]);
#pragma unroll
      for (int nf = 0; nf < 6; ++nf)
        b[nf] = *(const bf16x8*)(&Bs[wn * 96 + nf * 16 + lr][ks * 32 + lg * 8]);
#pragma unroll
      for (int mf = 0; mf < 4; ++mf)
#pragma unroll
        for (int nf = 0; nf < 6; ++nf)
          acc[mf][nf] = __builtin_amdgcn_mfma_f32_16x16x32_bf16(
              a[mf], b[nf], acc[mf][nf], 0, 0, 0);
    }
  }
#pragma unroll
  for (int mf = 0; mf < 4; ++mf)
#pragma unroll
    for (int nf = 0; nf < 6; ++nf) {
      int n = wn * 96 + nf * 16 + lr;
      long rowb = m0 + wm * 64 + mf * 16 + lg * 4;
#pragma unroll
      for (int r = 0; r < 4; ++r) {
        long idx = (rowb + r) * 192 + n;
        outp[idx] = acc[mf][nf][r] + bias[n] + bf2f(residb[idx]);
      }
    }
}

// ---------- windowed attention: one wave per (window, head); linear IO ----
__global__ __launch_bounds__(64) void attn_kernel(const short* __restrict__ qkv,
                                                  const float* __restrict__ rpb,
                                                  short* __restrict__ y) {
  __shared__ short vT[32][72];  // [d][token]
  __shared__ short P[64][72];   // [q][k]
  const int lane = threadIdx.x;
  const int bid = blockIdx.x;
  const int h = bid % 6;
  const long wglob = bid / 6;        // b*1024 + w
  const int w = (int)wglob & 1023;
  const int wr = w >> 5, wc = w & 31;
  const long wbase = wglob * 64;
  const int lr = lane & 15, lg = lane >> 4;

  bf16x8 aq[4], bk[4];
#pragma unroll
  for (int i = 0; i < 4; ++i) {
    long rq = wbase + i * 16 + lr;
    aq[i] = *(const bf16x8*)(qkv + rq * 576 + h * 32 + lg * 8);
    bk[i] = *(const bf16x8*)(qkv + rq * 576 + 192 + h * 32 + lg * 8);
  }
  {  // stage V transposed: vT[d][token]
    const short* vp = qkv + (wbase + lane) * 576 + 384 + h * 32;
#pragma unroll
    for (int q4 = 0; q4 < 4; ++q4) {
      bf16x8 vv = *(const bf16x8*)(vp + q4 * 8);
#pragma unroll
      for (int j = 0; j < 8; ++j) vT[q4 * 8 + j][lane] = vv[j];
    }
  }

  f32x4 s[4][4] = {};
#pragma unroll
  for (int mi = 0; mi < 4; ++mi)
#pragma unroll
    for (int ni = 0; ni < 4; ++ni)
      s[mi][ni] = __builtin_amdgcn_mfma_f32_16x16x32_bf16(aq[mi], bk[ni],
                                                          s[mi][ni], 0, 0, 0);

  const float SCALE = 0.17677669529663687f;
  float rinv[4][4];
#pragma unroll
  for (int mi = 0; mi < 4; ++mi) {
#pragma unroll
    for (int r = 0; r < 4; ++r) {
      int q = mi * 16 + lg * 4 + r;
      int qh = wr * 8 + (q >> 3), qw = wc * 8 + (q & 7);  // shifted coords
      int ridq = 3 * ((qh < 248) ? 0 : ((qh < 252) ? 1 : 2)) +
                 ((qw < 248) ? 0 : ((qw < 252) ? 1 : 2));
      float lv[4];
      float mx = -1e30f;
#pragma unroll
      for (int ni = 0; ni < 4; ++ni) {
        int k = ni * 16 + lr;
        int dr = (q >> 3) - (k >> 3) + 7;
        int dc = (q & 7) - (k & 7) + 7;
        float bias = rpb[(dr * 15 + dc) * 6 + h];
        int kh = wr * 8 + (k >> 3), kw = wc * 8 + (k & 7);
        int ridk = 3 * ((kh < 248) ? 0 : ((kh < 252) ? 1 : 2)) +
                   ((kw < 248) ? 0 : ((kw < 252) ? 1 : 2));
        float lvv = s[mi][ni][r] * SCALE + bias + ((ridq != ridk) ? -100.0f : 0.0f);
        lv[ni] = lvv;
        mx = fmaxf(mx, lvv);
      }
#pragma unroll
      for (int m = 1; m < 16; m <<= 1) mx = fmaxf(mx, __shfl_xor(mx, m));
      float sum = 0.0f;
#pragma unroll
      for (int ni = 0; ni < 4; ++ni) {
        float p = expf(lv[ni] - mx);
        lv[ni] = p;
        sum += p;
      }
#pragma unroll
      for (int m = 1; m < 16; m <<= 1) sum += __shfl_xor(sum, m);
      rinv[mi][r] = 1.0f / sum;
#pragma unroll
      for (int ni = 0; ni < 4; ++ni) P[q][ni * 16 + lr] = f2bf(lv[ni]);
    }
  }
  __syncthreads();

  f32x4 o[4][2] = {};
#pragma unroll
  for (int ks = 0; ks < 2; ++ks) {
    bf16x8 ap[4], bv[2];
#pragma unroll
    for (int mi = 0; mi < 4; ++mi)
      ap[mi] = *(const bf16x8*)(&P[mi * 16 + lr][ks * 32 + lg * 8]);
#pragma unroll
    for (int ni = 0; ni < 2; ++ni)
      bv[ni] = *(const bf16x8*)(&vT[ni * 16 + lr][ks * 32 + lg * 8]);
#pragma unroll
    for (int mi = 0; mi < 4; ++mi)
#pragma unroll
      for (int ni = 0; ni < 2; ++ni)
        o[mi][ni] = __builtin_amdgcn_mfma_f32_16x16x32_bf16(ap[mi], bv[ni],
                                                            o[mi][ni], 0, 0, 0);
  }
#pragma unroll
  for (int mi = 0; mi < 4; ++mi) {
#pragma unroll
    for (int r = 0; r < 4; ++r) {
      int q = mi * 16 + lg * 4 + r;
      float ri = rinv[mi][r];
#pragma unroll
      for (int ni = 0; ni < 2; ++ni)
        y[(wbase + q) * 192 + h * 32 + ni * 16 + lr] = f2bf(o[mi][ni][r] * ri);
    }
  }
}

// ---------- depthwise 3x3 conv + GELU, weights in registers ----------
// one thread: fixed (cg, px), strip of 16 output rows; 9 activation loads/pixel
// hbc: [130 slots][256][768] bf16, slot j = global y (yh*128 - 1 + j)
// h2c: [128][256][768] bf16, rows y = yh*128 + py
__global__ __launch_bounds__(256) void dwconv_kernel(const short* __restrict__ hbc,
                                                     const float* __restrict__ dww,
                                                     const float* __restrict__ dwb,
                                                     short* __restrict__ h2c,
                                                     int yh) {
  int t = blockIdx.x * 256 + threadIdx.x;  // over cg*px: 96*256 = 24576
  int cg = t % 96;
  int px = t / 96;
  int strip = blockIdx.y;  // 0..7 -> py = strip*16 .. +15

  // 72 weights + 8 biases into registers (amortized over 16 pixels)
  float wv[9][8];
#pragma unroll
  for (int tap = 0; tap < 9; ++tap) {
    float4 a = *(const float4*)(dww + tap * 768 + cg * 8);
    float4 b = *(const float4*)(dww + tap * 768 + cg * 8 + 4);
    wv[tap][0] = a.x; wv[tap][1] = a.y; wv[tap][2] = a.z; wv[tap][3] = a.w;
    wv[tap][4] = b.x; wv[tap][5] = b.y; wv[tap][6] = b.z; wv[tap][7] = b.w;
  }
  float bias[8];
  {
    float4 a = *(const float4*)(dwb + cg * 8);
    float4 b = *(const float4*)(dwb + cg * 8 + 4);
    bias[0] = a.x; bias[1] = a.y; bias[2] = a.z; bias[3] = a.w;
    bias[4] = b.x; bias[5] = b.y; bias[6] = b.z; bias[7] = b.w;
  }

#pragma unroll 2
  for (int pp = 0; pp < 16; ++pp) {
    int py = strip * 16 + pp;
    int ybase = yh * 128 + py;
    float acc[8];
#pragma unroll
    for (int j = 0; j < 8; ++j) acc[j] = bias[j];
#pragma unroll
    for (int dy = 0; dy < 3; ++dy) {
      int yy = ybase + dy - 1;
      if (yy < 0 || yy > 255) continue;
      int slot = py + dy;
#pragma unroll
      for (int dx = 0; dx < 3; ++dx) {
        int xx = px + dx - 1;
        if (xx < 0 || xx > 255) continue;
        bf16x8 hv = *(const bf16x8*)(hbc + ((long)slot * 256 + xx) * 768 + cg * 8);
#pragma unroll
        for (int j = 0; j < 8; ++j) acc[j] += bf2f(hv[j]) * wv[dy * 3 + dx][j];
      }
    }
    bf16x8 ov;
#pragma unroll
    for (int j = 0; j < 8; ++j) ov[j] = f2bf(gelu_exact(acc[j]));
    *(bf16x8*)(h2c + ((long)py * 256 + px) * 768 + cg * 8) = ov;
  }
}

// ---------- launch ----------
extern "C" void kernel_launch(void* const* d_in, const int* in_sizes, int n_in,
                              void* d_out, int out_size, void* d_ws, size_t ws_size,
                              hipStream_t stream) {
  const float* x = (const float*)d_in[0];
  const float* n1w = (const float*)d_in[1];
  const float* n1b = (const float*)d_in[2];
  const float* q_w = (const float*)d_in[3];
  const float* q_b = (const float*)d_in[4];
  const float* kv_w = (const float*)d_in[5];
  const float* kv_b = (const float*)d_in[6];
  const float* rpb = (const float*)d_in[7];
  const float* proj_w = (const float*)d_in[8];
  const float* proj_b = (const float*)d_in[9];
  const float* n2w = (const float*)d_in[10];
  const float* n2b = (const float*)d_in[11];
  const float* l1_w = (const float*)d_in[12];
  const float* l1_b = (const float*)d_in[13];
  const float* dw_w = (const float*)d_in[14];
  const float* dw_b = (const float*)d_in[15];
  const float* l2_w = (const float*)d_in[16];
  const float* l2_b = (const float*)d_in[17];
  float* out = (float*)d_out;

  // ---- workspace: total ~252.5 MB ----
  char* ws = (char*)d_ws;
  short* xn = (short*)ws;                     // [0,48M): xn(win) -> yb -> xn2
  short* qkv = (short*)(ws + 50331648);       // [48M,192M) window order
  short* hbc = (short*)(ws + 50331648);       // reuse: 51,118,080 B
  short* h2c = (short*)(ws + 101449728);      // 50,331,648 B (ends 144.7M)
  short* x2bf = (short*)(ws + 201326592);     // [192M,240M) token order bf16
  short* bt1 = (short*)(ws + 251658240);      // [576][192]
  short* bt2 = bt1 + 110592;                  // [192][192]
  short* bt3 = bt2 + 36864;                   // [768][192]
  short* bt4 = bt3 + 147456;                  // [192][768]
  short* yb = xn;
  short* xn2 = xn;

  wprep_kernel<<<144, 256, 0, stream>>>(q_w, bt1, 192, 192);
  wprep_kernel<<<288, 256, 0, stream>>>(kv_w, bt1 + 36864, 192, 384);
  wprep_kernel<<<144, 256, 0, stream>>>(proj_w, bt2, 192, 192);
  wprep_kernel<<<576, 256, 0, stream>>>(l1_w, bt3, 192, 768);
  wprep_kernel<<<576, 256, 0, stream>>>(l2_w, bt4, 768, 192);

  ln1_kernel<<<32768, 256, 0, stream>>>(x, n1w, n1b, xn);
  // qkv: 1024 m-tiles, 9 n-blocks; grid 8 xcd * 16 mg * 9 n = 1152
  gemm1_kernel<576, 0><<<1152, 256, 0, stream>>>(xn, bt1, q_b, kv_b, nullptr,
                                                 qkv, 9, 16, 8, 1024);
  attn_kernel<<<12288, 64, 0, stream>>>(qkv, rpb, yb);
  // proj: 1024 m-tiles, 3 n-blocks; grid 8*16*3 = 384; unperm + resid(x fp32)
  gemm1_kernel<192, 3><<<384, 256, 0, stream>>>(yb, bt2, proj_b, nullptr, x,
                                                x2bf, 3, 16, 8, 1024);
  ln2_kernel<<<32768, 256, 0, stream>>>(x2bf, n2w, n2b, xn2);

  // LeFF in 4 chunks: (batch b, y-half yh), 129 rows with 1-row conv halo
  for (int c = 0; c < 4; ++c) {
    int b = c >> 1, yh = c & 1;
    int ystart = yh ? 127 : 0;
    int s0 = yh ? 0 : 1;
    long tok0 = (long)b * 65536 + (long)ystart * 256;
    long ooff = ((long)b * 65536 + (long)yh * 32768) * 192;
    // l1: 258 m-tiles, 12 n-blocks; grid 8*6*12 = 576 (tail-guarded)
    gemm1_kernel<768, 2><<<576, 256, 0, stream>>>(
        xn2 + tok0 * 192, bt3, l1_b, nullptr, nullptr,
        hbc + (long)s0 * 196608, 12, 6, 6, 258);
    dwconv_kernel<<<dim3(96, 8), 256, 0, stream>>>(hbc, dw_w, dw_b, h2c, yh);
    // l2: 256 m-tiles, full N=192 per block
    gemm2_kernel<<<256, 256, 0, stream>>>(h2c, bt4, l2_b, x2bf + ooff,
                                          out + ooff);
  }
}

// Round 6
// 825.987 us; speedup vs baseline: 1.6963x; 1.0240x over previous
//
#include <hip/hip_runtime.h>
#include <math.h>

typedef float f32x4 __attribute__((ext_vector_type(4)));
typedef short bf16x8 __attribute__((ext_vector_type(8)));

__device__ __forceinline__ short f2bf(float f) {
  unsigned u = __builtin_bit_cast(unsigned, f);
  u = (u + 0x7FFFu + ((u >> 16) & 1u)) >> 16;
  return (short)u;
}
__device__ __forceinline__ float bf2f(short s) {
  unsigned u = ((unsigned)(unsigned short)s) << 16;
  return __builtin_bit_cast(float, u);
}
__device__ __forceinline__ float gelu_exact(float x) {
  return 0.5f * x * (1.0f + erff(x * 0.70710678118654752f));
}

// window-order row for original pixel row (b, ho, wo): shift by -4 then partition
__device__ __forceinline__ long perm_row(int b, int ho, int wo) {
  int hs = (ho + 252) & 255, ws = (wo + 252) & 255;
  int w = ((hs >> 3) << 5) | (ws >> 3);
  int t = ((hs & 7) << 3) | (ws & 7);
  return ((long)b << 16) | (w << 6) | t;
}
// inverse: window-order row -> original row
__device__ __forceinline__ long unperm_row(long m) {
  int b = (int)(m >> 16);
  int w = ((int)m >> 6) & 1023, t = (int)m & 63;
  int hs = ((w >> 5) << 3) | (t >> 3);
  int ws = ((w & 31) << 3) | (t & 7);
  int ho = (hs + 4) & 255, wo = (ws + 4) & 255;
  return ((long)b << 16) | (ho << 8) | wo;
}

// ---------- LN1: fp32 token-order in -> bf16 window-order out ----------
__global__ __launch_bounds__(256) void ln1_kernel(const float* __restrict__ x,
                                                  const float* __restrict__ w,
                                                  const float* __restrict__ b,
                                                  short* __restrict__ out) {
  int lane = threadIdx.x & 63;
  long row = (long)blockIdx.x * 4 + (threadIdx.x >> 6);
  const float* xr = x + row * 192;
  float v0 = xr[lane], v1 = xr[lane + 64], v2 = xr[lane + 128];
  float s = v0 + v1 + v2, s2 = v0 * v0 + v1 * v1 + v2 * v2;
#pragma unroll
  for (int m = 1; m < 64; m <<= 1) {
    s += __shfl_xor(s, m);
    s2 += __shfl_xor(s2, m);
  }
  float mu = s * (1.0f / 192.0f);
  float rstd = rsqrtf(s2 * (1.0f / 192.0f) - mu * mu + 1e-5f);
  long drow = perm_row((int)(row >> 16), ((int)row >> 8) & 255, (int)row & 255);
  short* o = out + drow * 192;
  o[lane] = f2bf((v0 - mu) * rstd * w[lane] + b[lane]);
  o[lane + 64] = f2bf((v1 - mu) * rstd * w[lane + 64] + b[lane + 64]);
  o[lane + 128] = f2bf((v2 - mu) * rstd * w[lane + 128] + b[lane + 128]);
}

// ---------- LN2: bf16 token-order in -> bf16 token-order out ----------
__global__ __launch_bounds__(256) void ln2_kernel(const short* __restrict__ x,
                                                  const float* __restrict__ w,
                                                  const float* __restrict__ b,
                                                  short* __restrict__ out) {
  int lane = threadIdx.x & 63;
  long row = (long)blockIdx.x * 4 + (threadIdx.x >> 6);
  const short* xr = x + row * 192;
  float v0 = bf2f(xr[lane]), v1 = bf2f(xr[lane + 64]), v2 = bf2f(xr[lane + 128]);
  float s = v0 + v1 + v2, s2 = v0 * v0 + v1 * v1 + v2 * v2;
#pragma unroll
  for (int m = 1; m < 64; m <<= 1) {
    s += __shfl_xor(s, m);
    s2 += __shfl_xor(s2, m);
  }
  float mu = s * (1.0f / 192.0f);
  float rstd = rsqrtf(s2 * (1.0f / 192.0f) - mu * mu + 1e-5f);
  short* o = out + row * 192;
  o[lane] = f2bf((v0 - mu) * rstd * w[lane] + b[lane]);
  o[lane + 64] = f2bf((v1 - mu) * rstd * w[lane + 64] + b[lane + 64]);
  o[lane + 128] = f2bf((v2 - mu) * rstd * w[lane + 128] + b[lane + 128]);
}

// ---------- weight prep: W[K][N] fp32 -> Bt[N][K] bf16 ----------
__global__ __launch_bounds__(256) void wprep_kernel(const float* __restrict__ w,
                                                    short* __restrict__ bt,
                                                    int K, int N) {
  long i = (long)blockIdx.x * 256 + threadIdx.x;
  if (i >= (long)K * N) return;
  int n = (int)(i / K), k = (int)(i % K);
  bt[i] = f2bf(w[(long)k * N + n]);
}

// ---------- attention bias table: [h][q][k], pre-scaled by log2(e) ----------
__global__ __launch_bounds__(256) void bias_prep(const float* __restrict__ rpb,
                                                 float* __restrict__ biasTab) {
  int i = blockIdx.x * 256 + threadIdx.x;  // 6*64*64 = 24576
  int k = i & 63, q = (i >> 6) & 63, h = i >> 12;
  int dr = (q >> 3) - (k >> 3) + 7;
  int dc = (q & 7) - (k & 7) + 7;
  biasTab[i] = rpb[(dr * 15 + dc) * 6 + h] * 1.4426950408889634f;
}

// ---------- GEMM (K=192): B in regs, in-kernel m-loop, XCD-exact mapping ----
// EPI 0: + bias(B0 col<192 / B1 col>=192)       -> bf16  (qkv, window order)
// EPI 2: gelu(+ bias)                            -> bf16  (l1)
// EPI 3: + bias + resid fp32 @unperm row, unperm -> bf16  (proj)
template <int NTOT, int EPI>
__global__ __launch_bounds__(256) void gemm1_kernel(
    const short* __restrict__ A, const short* __restrict__ Bt,
    const float* __restrict__ B0, const float* __restrict__ B1,
    const float* __restrict__ residf, short* __restrict__ outp,
    int nblk, int mgx, int iters, int mtiles) {
  __shared__ short As[128][200];
  const int tid = threadIdx.x;
  const int lane = tid & 63, wid = tid >> 6;
  const int lr = lane & 15, lg = lane >> 4;
  const int xcd = blockIdx.x & 7;
  const int i = blockIdx.x >> 3;
  const int n0 = (i % nblk) * 64;
  const int mg = xcd * mgx + i / nblk;

  bf16x8 bf[6][4];
#pragma unroll
  for (int ks = 0; ks < 6; ++ks)
#pragma unroll
    for (int ni = 0; ni < 4; ++ni)
      bf[ks][ni] = *(const bf16x8*)(Bt + (long)(n0 + ni * 16 + lr) * 192 +
                                    ks * 32 + lg * 8);

#pragma unroll 1
  for (int it = 0; it < iters; ++it) {
    int mt = mg * iters + it;
    if (mt >= mtiles) continue;  // block-uniform
    long m0 = (long)mt * 128;
    __syncthreads();
#pragma unroll
    for (int p = 0; p < 12; ++p) {
      int ci = tid + p * 256;
      int r = ci / 24, c = ci % 24;
      *(float4*)(&As[r][c * 8]) = *(const float4*)(A + (m0 + r) * 192 + c * 8);
    }
    __syncthreads();
    f32x4 acc[2][4] = {};
#pragma unroll
    for (int ks = 0; ks < 6; ++ks) {
      bf16x8 a0 = *(const bf16x8*)(&As[wid * 32 + lr][ks * 32 + lg * 8]);
      bf16x8 a1 = *(const bf16x8*)(&As[wid * 32 + 16 + lr][ks * 32 + lg * 8]);
#pragma unroll
      for (int ni = 0; ni < 4; ++ni) {
        acc[0][ni] = __builtin_amdgcn_mfma_f32_16x16x32_bf16(a0, bf[ks][ni],
                                                             acc[0][ni], 0, 0, 0);
        acc[1][ni] = __builtin_amdgcn_mfma_f32_16x16x32_bf16(a1, bf[ks][ni],
                                                             acc[1][ni], 0, 0, 0);
      }
    }
    // epilogue: C layout col=lane&15, row=(lane>>4)*4+reg
#pragma unroll
    for (int mi = 0; mi < 2; ++mi) {
#pragma unroll
      for (int ni = 0; ni < 4; ++ni) {
        int n = n0 + ni * 16 + lr;
        long rowb = m0 + wid * 32 + mi * 16 + lg * 4;
#pragma unroll
        for (int r = 0; r < 4; ++r) {
          float v = acc[mi][ni][r];
          long m = rowb + r;
          if constexpr (EPI == 0) {
            float bb = (n < 192) ? B0[n] : B1[n - 192];
            outp[m * NTOT + n] = f2bf(v + bb);
          } else if constexpr (EPI == 2) {
            outp[m * NTOT + n] = f2bf(gelu_exact(v + B0[n]));
          } else {
            long oidx = unperm_row(m) * 192 + n;
            outp[oidx] = f2bf(v + B0[n] + residf[oidx]);
          }
        }
      }
    }
  }
}

// ---------- GEMM K=768 (l2): A+B staged in LDS, BM=128 x BN=192 ----------
__global__ __launch_bounds__(256) void gemm2_kernel(
    const short* __restrict__ A, const short* __restrict__ Bt,
    const float* __restrict__ bias, const short* __restrict__ residb,
    float* __restrict__ outp) {
  __shared__ short As[128][72];
  __shared__ short Bs[192][72];
  const int tid = threadIdx.x;
  const int lane = tid & 63, wid = tid >> 6;
  const int lr = lane & 15, lg = lane >> 4;
  const int wm = wid >> 1, wn = wid & 1;  // 2x2 waves: 64 rows x 96 cols each
  const long m0 = (long)blockIdx.x * 128;

  f32x4 acc[4][6] = {};
#pragma unroll 1
  for (int kc = 0; kc < 12; ++kc) {
    __syncthreads();
#pragma unroll
    for (int p = 0; p < 4; ++p) {  // A: 128x64 = 1024 chunks
      int g = p * 256 + tid;
      int r = g >> 3, c = g & 7;
      *(float4*)(&As[r][c * 8]) =
          *(const float4*)(A + (m0 + r) * 768 + kc * 64 + c * 8);
    }
#pragma unroll
    for (int p = 0; p < 6; ++p) {  // B: 192x64 = 1536 chunks
      int g = p * 256 + tid;
      int n = g >> 3, c = g & 7;
      *(float4*)(&Bs[n][c * 8]) =
          *(const float4*)(Bt + (long)n * 768 + kc * 64 + c * 8);
    }
    __syncthreads();
#pragma unroll
    for (int ks = 0; ks < 2; ++ks) {
      bf16x8 a[4], b[6];
#pragma unroll
      for (int mf = 0; mf < 4; ++mf)
        a[mf] = *(const bf16x8*)(&As[wm * 64 + mf * 16 + lr][ks * 32 + lg * 8]);
#pragma unroll
      for (int nf = 0; nf < 6; ++nf)
        b[nf] = *(const bf16x8*)(&Bs[wn * 96 + nf * 16 + lr][ks * 32 + lg * 8]);
#pragma unroll
      for (int mf = 0; mf < 4; ++mf)
#pragma unroll
        for (int nf = 0; nf < 6; ++nf)
          acc[mf][nf] = __builtin_amdgcn_mfma_f32_16x16x32_bf16(
              a[mf], b[nf], acc[mf][nf], 0, 0, 0);
    }
  }
#pragma unroll
  for (int mf = 0; mf < 4; ++mf)
#pragma unroll
    for (int nf = 0; nf < 6; ++nf) {
      int n = wn * 96 + nf * 16 + lr;
      long rowb = m0 + wm * 64 + mf * 16 + lg * 4;
#pragma unroll
      for (int r = 0; r < 4; ++r) {
        long idx = (rowb + r) * 192 + n;
        outp[idx] = acc[mf][nf][r] + bias[n] + bf2f(residb[idx]);
      }
    }
}

// ---------- windowed attention: one wave per (window, head) ----------
// bid XCD-swizzled: all 6 heads of a window on the same XCD (L2 row reuse)
__global__ __launch_bounds__(64) void attn_kernel(const short* __restrict__ qkv,
                                                  const float* __restrict__ biasTab,
                                                  short* __restrict__ y) {
  __shared__ short vT[32][72];  // [d][token]
  __shared__ short P[64][72];   // [q][k]
  const int lane = threadIdx.x;
  const int bid = blockIdx.x;
  const int xcd = bid & 7;
  const int j = bid >> 3;            // 0..1535
  const int wglob = xcd * 256 + j / 6;  // 0..2047 (b*1024 + w)
  const int h = j % 6;
  const int w = wglob & 1023;
  const int wr = w >> 5, wc = w & 31;
  const long wbase = (long)wglob * 64;
  const int lr = lane & 15, lg = lane >> 4;

  bf16x8 aq[4], bk[4];
#pragma unroll
  for (int i = 0; i < 4; ++i) {
    long rq = wbase + i * 16 + lr;
    aq[i] = *(const bf16x8*)(qkv + rq * 576 + h * 32 + lg * 8);
    bk[i] = *(const bf16x8*)(qkv + rq * 576 + 192 + h * 32 + lg * 8);
  }
  {  // stage V transposed: vT[d][token]
    const short* vp = qkv + (wbase + lane) * 576 + 384 + h * 32;
#pragma unroll
    for (int q4 = 0; q4 < 4; ++q4) {
      bf16x8 vv = *(const bf16x8*)(vp + q4 * 8);
#pragma unroll
      for (int jj = 0; jj < 8; ++jj) vT[q4 * 8 + jj][lane] = vv[jj];
    }
  }

  f32x4 s[4][4] = {};
#pragma unroll
  for (int mi = 0; mi < 4; ++mi)
#pragma unroll
    for (int ni = 0; ni < 4; ++ni)
      s[mi][ni] = __builtin_amdgcn_mfma_f32_16x16x32_bf16(aq[mi], bk[ni],
                                                          s[mi][ni], 0, 0, 0);

  // softmax in log2 domain: S*scale*log2e + biasTab(prescaled) + mask*log2e
  const float SCL2 = 0.17677669529663687f * 1.4426950408889634f;
  const float MASKC = -144.26950408889634f;
  const bool edge = (wr == 31) || (wc == 31);
  int ridk[4] = {0, 0, 0, 0};
  if (edge) {
#pragma unroll
    for (int ni = 0; ni < 4; ++ni) {
      int k = ni * 16 + lr;
      int kh = wr * 8 + (k >> 3), kw = wc * 8 + (k & 7);
      ridk[ni] = 3 * ((kh < 248) ? 0 : ((kh < 252) ? 1 : 2)) +
                 ((kw < 248) ? 0 : ((kw < 252) ? 1 : 2));
    }
  }

  float rinv[4][4];
#pragma unroll
  for (int mi = 0; mi < 4; ++mi) {
#pragma unroll
    for (int r = 0; r < 4; ++r) {
      int q = mi * 16 + lg * 4 + r;
      const float* bp = biasTab + (h << 12) + (q << 6);
      int ridq = 0;
      if (edge) {
        int qh = wr * 8 + (q >> 3), qw = wc * 8 + (q & 7);
        ridq = 3 * ((qh < 248) ? 0 : ((qh < 252) ? 1 : 2)) +
               ((qw < 248) ? 0 : ((qw < 252) ? 1 : 2));
      }
      float lv[4];
      float mx = -1e30f;
#pragma unroll
      for (int ni = 0; ni < 4; ++ni) {
        float lvv = s[mi][ni][r] * SCL2 + bp[ni * 16 + lr];
        if (edge && ridq != ridk[ni]) lvv += MASKC;
        lv[ni] = lvv;
        mx = fmaxf(mx, lvv);
      }
#pragma unroll
      for (int m = 1; m < 16; m <<= 1) mx = fmaxf(mx, __shfl_xor(mx, m));
      float sum = 0.0f;
#pragma unroll
      for (int ni = 0; ni < 4; ++ni) {
        float p = exp2f(lv[ni] - mx);
        lv[ni] = p;
        sum += p;
      }
#pragma unroll
      for (int m = 1; m < 16; m <<= 1) sum += __shfl_xor(sum, m);
      rinv[mi][r] = 1.0f / sum;
#pragma unroll
      for (int ni = 0; ni < 4; ++ni) P[q][ni * 16 + lr] = f2bf(lv[ni]);
    }
  }
  __syncthreads();

  f32x4 o[4][2] = {};
#pragma unroll
  for (int ks = 0; ks < 2; ++ks) {
    bf16x8 ap[4], bv[2];
#pragma unroll
    for (int mi = 0; mi < 4; ++mi)
      ap[mi] = *(const bf16x8*)(&P[mi * 16 + lr][ks * 32 + lg * 8]);
#pragma unroll
    for (int ni = 0; ni < 2; ++ni)
      bv[ni] = *(const bf16x8*)(&vT[ni * 16 + lr][ks * 32 + lg * 8]);
#pragma unroll
    for (int mi = 0; mi < 4; ++mi)
#pragma unroll
      for (int ni = 0; ni < 2; ++ni)
        o[mi][ni] = __builtin_amdgcn_mfma_f32_16x16x32_bf16(ap[mi], bv[ni],
                                                            o[mi][ni], 0, 0, 0);
  }
#pragma unroll
  for (int mi = 0; mi < 4; ++mi) {
#pragma unroll
    for (int r = 0; r < 4; ++r) {
      int q = mi * 16 + lg * 4 + r;
      float ri = rinv[mi][r];
#pragma unroll
      for (int ni = 0; ni < 2; ++ni)
        y[(wbase + q) * 192 + h * 32 + ni * 16 + lr] = f2bf(o[mi][ni][r] * ri);
    }
  }
}

// ---------- depthwise 3x3 conv + GELU, weights in registers ----------
__global__ __launch_bounds__(256) void dwconv_kernel(const short* __restrict__ hbc,
                                                     const float* __restrict__ dww,
                                                     const float* __restrict__ dwb,
                                                     short* __restrict__ h2c,
                                                     int yh) {
  int t = blockIdx.x * 256 + threadIdx.x;  // over cg*px: 96*256 = 24576
  int cg = t % 96;
  int px = t / 96;
  int strip = blockIdx.y;  // 0..7 -> py = strip*16 .. +15

  float wv[9][8];
#pragma unroll
  for (int tap = 0; tap < 9; ++tap) {
    float4 a = *(const float4*)(dww + tap * 768 + cg * 8);
    float4 b = *(const float4*)(dww + tap * 768 + cg * 8 + 4);
    wv[tap][0] = a.x; wv[tap][1] = a.y; wv[tap][2] = a.z; wv[tap][3] = a.w;
    wv[tap][4] = b.x; wv[tap][5] = b.y; wv[tap][6] = b.z; wv[tap][7] = b.w;
  }
  float bias[8];
  {
    float4 a = *(const float4*)(dwb + cg * 8);
    float4 b = *(const float4*)(dwb + cg * 8 + 4);
    bias[0] = a.x; bias[1] = a.y; bias[2] = a.z; bias[3] = a.w;
    bias[4] = b.x; bias[5] = b.y; bias[6] = b.z; bias[7] = b.w;
  }

#pragma unroll 2
  for (int pp = 0; pp < 16; ++pp) {
    int py = strip * 16 + pp;
    int ybase = yh * 128 + py;
    float acc[8];
#pragma unroll
    for (int j = 0; j < 8; ++j) acc[j] = bias[j];
#pragma unroll
    for (int dy = 0; dy < 3; ++dy) {
      int yy = ybase + dy - 1;
      if (yy < 0 || yy > 255) continue;
      int slot = py + dy;
#pragma unroll
      for (int dx = 0; dx < 3; ++dx) {
        int xx = px + dx - 1;
        if (xx < 0 || xx > 255) continue;
        bf16x8 hv = *(const bf16x8*)(hbc + ((long)slot * 256 + xx) * 768 + cg * 8);
#pragma unroll
        for (int j = 0; j < 8; ++j) acc[j] += bf2f(hv[j]) * wv[dy * 3 + dx][j];
      }
    }
    bf16x8 ov;
#pragma unroll
    for (int j = 0; j < 8; ++j) ov[j] = f2bf(gelu_exact(acc[j]));
    *(bf16x8*)(h2c + ((long)py * 256 + px) * 768 + cg * 8) = ov;
  }
}

// ---------- launch ----------
extern "C" void kernel_launch(void* const* d_in, const int* in_sizes, int n_in,
                              void* d_out, int out_size, void* d_ws, size_t ws_size,
                              hipStream_t stream) {
  const float* x = (const float*)d_in[0];
  const float* n1w = (const float*)d_in[1];
  const float* n1b = (const float*)d_in[2];
  const float* q_w = (const float*)d_in[3];
  const float* q_b = (const float*)d_in[4];
  const float* kv_w = (const float*)d_in[5];
  const float* kv_b = (const float*)d_in[6];
  const float* rpb = (const float*)d_in[7];
  const float* proj_w = (const float*)d_in[8];
  const float* proj_b = (const float*)d_in[9];
  const float* n2w = (const float*)d_in[10];
  const float* n2b = (const float*)d_in[11];
  const float* l1_w = (const float*)d_in[12];
  const float* l1_b = (const float*)d_in[13];
  const float* dw_w = (const float*)d_in[14];
  const float* dw_b = (const float*)d_in[15];
  const float* l2_w = (const float*)d_in[16];
  const float* l2_b = (const float*)d_in[17];
  float* out = (float*)d_out;

  // ---- workspace: total ~252.6 MB ----
  char* ws = (char*)d_ws;
  short* xn = (short*)ws;                     // [0,48M): xn(win) -> yb -> xn2
  short* qkv = (short*)(ws + 50331648);       // [48M,192M) window order
  short* hbc = (short*)(ws + 50331648);       // reuse: 51,118,080 B
  short* h2c = (short*)(ws + 101449728);      // 50,331,648 B (ends 144.7M)
  short* x2bf = (short*)(ws + 201326592);     // [192M,240M) token order bf16
  short* bt1 = (short*)(ws + 251658240);      // [576][192]
  short* bt2 = bt1 + 110592;                  // [192][192]
  short* bt3 = bt2 + 36864;                   // [768][192]
  short* bt4 = bt3 + 147456;                  // [192][768] ends 252,542,976
  float* biasTab = (float*)(ws + 252542976);  // 6*64*64 f32 = 98,304 B
  short* yb = xn;
  short* xn2 = xn;

  wprep_kernel<<<144, 256, 0, stream>>>(q_w, bt1, 192, 192);
  wprep_kernel<<<288, 256, 0, stream>>>(kv_w, bt1 + 36864, 192, 384);
  wprep_kernel<<<144, 256, 0, stream>>>(proj_w, bt2, 192, 192);
  wprep_kernel<<<576, 256, 0, stream>>>(l1_w, bt3, 192, 768);
  wprep_kernel<<<576, 256, 0, stream>>>(l2_w, bt4, 768, 192);
  bias_prep<<<96, 256, 0, stream>>>(rpb, biasTab);

  ln1_kernel<<<32768, 256, 0, stream>>>(x, n1w, n1b, xn);
  // qkv: 1024 m-tiles, 9 n-blocks, iters=2; grid 8 xcd * 64 mg * 9 n = 4608
  gemm1_kernel<576, 0><<<4608, 256, 0, stream>>>(xn, bt1, q_b, kv_b, nullptr,
                                                 qkv, 9, 64, 2, 1024);
  attn_kernel<<<12288, 64, 0, stream>>>(qkv, biasTab, yb);
  // proj: 1024 m-tiles, 3 n-blocks, iters=2; grid 8*64*3 = 1536
  gemm1_kernel<192, 3><<<1536, 256, 0, stream>>>(yb, bt2, proj_b, nullptr, x,
                                                 x2bf, 3, 64, 2, 1024);
  ln2_kernel<<<32768, 256, 0, stream>>>(x2bf, n2w, n2b, xn2);

  // LeFF in 4 chunks: (batch b, y-half yh), 129 rows with 1-row conv halo
  for (int c = 0; c < 4; ++c) {
    int b = c >> 1, yh = c & 1;
    int ystart = yh ? 127 : 0;
    int s0 = yh ? 0 : 1;
    long tok0 = (long)b * 65536 + (long)ystart * 256;
    long ooff = ((long)b * 65536 + (long)yh * 32768) * 192;
    // l1: 258 m-tiles, 12 n-blocks, iters=2; grid 8*17*12 = 1632 (tail-guarded)
    gemm1_kernel<768, 2><<<1632, 256, 0, stream>>>(
        xn2 + tok0 * 192, bt3, l1_b, nullptr, nullptr,
        hbc + (long)s0 * 196608, 12, 17, 2, 258);
    dwconv_kernel<<<dim3(96, 8), 256, 0, stream>>>(hbc, dw_w, dw_b, h2c, yh);
    // l2: 256 m-tiles, full N=192 per block
    gemm2_kernel<<<256, 256, 0, stream>>>(h2c, bt4, l2_b, x2bf + ooff,
                                          out + ooff);
  }
}

// Round 8
// 786.951 us; speedup vs baseline: 1.7805x; 1.0496x over previous
//
#include <hip/hip_runtime.h>
#include <math.h>

typedef float f32x4 __attribute__((ext_vector_type(4)));
typedef short bf16x8 __attribute__((ext_vector_type(8)));

__device__ __forceinline__ short f2bf(float f) {
  unsigned u = __builtin_bit_cast(unsigned, f);
  u = (u + 0x7FFFu + ((u >> 16) & 1u)) >> 16;
  return (short)u;
}
__device__ __forceinline__ float bf2f(short s) {
  unsigned u = ((unsigned)(unsigned short)s) << 16;
  return __builtin_bit_cast(float, u);
}
__device__ __forceinline__ float gelu_exact(float x) {
  return 0.5f * x * (1.0f + erff(x * 0.70710678118654752f));
}
// async global->LDS, 16B per lane; lds dest = wave-uniform base + lane*16
__device__ __forceinline__ void gld16(const short* g, short* l) {
  __builtin_amdgcn_global_load_lds(
      (const __attribute__((address_space(1))) void*)g,
      (__attribute__((address_space(3))) void*)l, 16, 0, 0);
}

// window-order row for original pixel row (b, ho, wo): shift by -4 then partition
__device__ __forceinline__ long perm_row(int b, int ho, int wo) {
  int hs = (ho + 252) & 255, ws = (wo + 252) & 255;
  int w = ((hs >> 3) << 5) | (ws >> 3);
  int t = ((hs & 7) << 3) | (ws & 7);
  return ((long)b << 16) | (w << 6) | t;
}
// inverse: window-order row -> original row
__device__ __forceinline__ long unperm_row(long m) {
  int b = (int)(m >> 16);
  int w = ((int)m >> 6) & 1023, t = (int)m & 63;
  int hs = ((w >> 5) << 3) | (t >> 3);
  int ws = ((w & 31) << 3) | (t & 7);
  int ho = (hs + 4) & 255, wo = (ws + 4) & 255;
  return ((long)b << 16) | (ho << 8) | wo;
}

// ---------- LN1: fp32 token-order in -> bf16 window-order out ----------
__global__ __launch_bounds__(256) void ln1_kernel(const float* __restrict__ x,
                                                  const float* __restrict__ w,
                                                  const float* __restrict__ b,
                                                  short* __restrict__ out) {
  int lane = threadIdx.x & 63;
  long row = (long)blockIdx.x * 4 + (threadIdx.x >> 6);
  const float* xr = x + row * 192;
  float v0 = xr[lane], v1 = xr[lane + 64], v2 = xr[lane + 128];
  float s = v0 + v1 + v2, s2 = v0 * v0 + v1 * v1 + v2 * v2;
#pragma unroll
  for (int m = 1; m < 64; m <<= 1) {
    s += __shfl_xor(s, m);
    s2 += __shfl_xor(s2, m);
  }
  float mu = s * (1.0f / 192.0f);
  float rstd = rsqrtf(s2 * (1.0f / 192.0f) - mu * mu + 1e-5f);
  long drow = perm_row((int)(row >> 16), ((int)row >> 8) & 255, (int)row & 255);
  short* o = out + drow * 192;
  o[lane] = f2bf((v0 - mu) * rstd * w[lane] + b[lane]);
  o[lane + 64] = f2bf((v1 - mu) * rstd * w[lane + 64] + b[lane + 64]);
  o[lane + 128] = f2bf((v2 - mu) * rstd * w[lane + 128] + b[lane + 128]);
}

// ---------- LN2: bf16 token-order in -> bf16 token-order out ----------
__global__ __launch_bounds__(256) void ln2_kernel(const short* __restrict__ x,
                                                  const float* __restrict__ w,
                                                  const float* __restrict__ b,
                                                  short* __restrict__ out) {
  int lane = threadIdx.x & 63;
  long row = (long)blockIdx.x * 4 + (threadIdx.x >> 6);
  const short* xr = x + row * 192;
  float v0 = bf2f(xr[lane]), v1 = bf2f(xr[lane + 64]), v2 = bf2f(xr[lane + 128]);
  float s = v0 + v1 + v2, s2 = v0 * v0 + v1 * v1 + v2 * v2;
#pragma unroll
  for (int m = 1; m < 64; m <<= 1) {
    s += __shfl_xor(s, m);
    s2 += __shfl_xor(s2, m);
  }
  float mu = s * (1.0f / 192.0f);
  float rstd = rsqrtf(s2 * (1.0f / 192.0f) - mu * mu + 1e-5f);
  short* o = out + row * 192;
  o[lane] = f2bf((v0 - mu) * rstd * w[lane] + b[lane]);
  o[lane + 64] = f2bf((v1 - mu) * rstd * w[lane + 64] + b[lane + 64]);
  o[lane + 128] = f2bf((v2 - mu) * rstd * w[lane + 128] + b[lane + 128]);
}

// ---------- weight prep: W[K][N] fp32 -> Bt[N][K] bf16 ----------
__global__ __launch_bounds__(256) void wprep_kernel(const float* __restrict__ w,
                                                    short* __restrict__ bt,
                                                    int K, int N) {
  long i = (long)blockIdx.x * 256 + threadIdx.x;
  if (i >= (long)K * N) return;
  int n = (int)(i / K), k = (int)(i % K);
  bt[i] = f2bf(w[(long)k * N + n]);
}

// ---------- attention bias table: [h][q][k], pre-scaled by log2(e) ----------
__global__ __launch_bounds__(256) void bias_prep(const float* __restrict__ rpb,
                                                 float* __restrict__ biasTab) {
  int i = blockIdx.x * 256 + threadIdx.x;  // 6*64*64 = 24576
  int k = i & 63, q = (i >> 6) & 63, h = i >> 12;
  int dr = (q >> 3) - (k >> 3) + 7;
  int dc = (q & 7) - (k & 7) + 7;
  biasTab[i] = rpb[(dr * 15 + dc) * 6 + h] * 1.4426950408889634f;
}

// ---------- GEMM (K=192): B in regs, global_load_lds A-staging (swizzled) ---
// LDS(r, c) = tile(r, c ^ ((r&7)<<4))  [byte addressing within 384B row]
// EPI 0: + bias(B0 col<192 / B1 col>=192)       -> bf16  (qkv, window order)
// EPI 2: gelu(+ bias)                            -> bf16  (l1)
// EPI 3: + bias + resid fp32 @unperm row, unperm -> bf16  (proj)
template <int NTOT, int EPI>
__global__ __launch_bounds__(256) void gemm1_kernel(
    const short* __restrict__ A, const short* __restrict__ Bt,
    const float* __restrict__ B0, const float* __restrict__ B1,
    const float* __restrict__ residf, short* __restrict__ outp,
    int nblk, int mgx, int iters, int mtiles) {
  __shared__ short As[128 * 192];  // linear tile, XOR-swizzled contents
  const int tid = threadIdx.x;
  const int lane = tid & 63, wid = tid >> 6;
  const int lr = lane & 15, lg = lane >> 4;
  const int xcd = blockIdx.x & 7;
  const int i = blockIdx.x >> 3;
  const int n0 = (i % nblk) * 64;
  const int mg = xcd * mgx + i / nblk;

  bf16x8 bf[6][4];
#pragma unroll
  for (int ks = 0; ks < 6; ++ks)
#pragma unroll
    for (int ni = 0; ni < 4; ++ni)
      bf[ks][ni] = *(const bf16x8*)(Bt + (long)(n0 + ni * 16 + lr) * 192 +
                                    ks * 32 + lg * 8);

  // 12 gload_lds per wave, 1024B each (64 lanes x 16B); per-lane source =
  // inverse-swizzled tile byte (r, c ^ ((r&7)<<4)) for lds byte lo
  int src_s[12];
#pragma unroll
  for (int s = 0; s < 12; ++s) {
    int lo = (wid * 12 + s) * 1024 + lane * 16;
    int r = lo / 384, c = lo % 384;
    src_s[s] = r * 192 + ((c ^ ((r & 7) << 4)) >> 1);
  }
  const int xorv = (lr & 7) << 4;

#pragma unroll 1
  for (int it = 0; it < iters; ++it) {
    int mt = mg * iters + it;
    if (mt >= mtiles) continue;  // block-uniform
    long m0 = (long)mt * 128;
    const short* Ab = A + m0 * 192;
    __syncthreads();  // prev tile's LDS reads done
#pragma unroll
    for (int s = 0; s < 12; ++s)
      gld16(Ab + src_s[s], As + (wid * 12 + s) * 512);
    __syncthreads();  // drains vmcnt (gload_lds) in all waves
    f32x4 acc[2][4] = {};
#pragma unroll
    for (int ks = 0; ks < 6; ++ks) {
      const char* asb = (const char*)As;
      const int col = (ks * 64 + lg * 16) ^ xorv;
      bf16x8 a0 = *(const bf16x8*)(asb + (wid * 32 + lr) * 384 + col);
      bf16x8 a1 = *(const bf16x8*)(asb + (wid * 32 + 16 + lr) * 384 + col);
#pragma unroll
      for (int ni = 0; ni < 4; ++ni) {
        acc[0][ni] = __builtin_amdgcn_mfma_f32_16x16x32_bf16(a0, bf[ks][ni],
                                                             acc[0][ni], 0, 0, 0);
        acc[1][ni] = __builtin_amdgcn_mfma_f32_16x16x32_bf16(a1, bf[ks][ni],
                                                             acc[1][ni], 0, 0, 0);
      }
    }
    // epilogue: C layout col=lane&15, row=(lane>>4)*4+reg
#pragma unroll
    for (int mi = 0; mi < 2; ++mi) {
#pragma unroll
      for (int ni = 0; ni < 4; ++ni) {
        int n = n0 + ni * 16 + lr;
        long rowb = m0 + wid * 32 + mi * 16 + lg * 4;
#pragma unroll
        for (int r = 0; r < 4; ++r) {
          float v = acc[mi][ni][r];
          long m = rowb + r;
          if constexpr (EPI == 0) {
            float bb = (n < 192) ? B0[n] : B1[n - 192];
            outp[m * NTOT + n] = f2bf(v + bb);
          } else if constexpr (EPI == 2) {
            outp[m * NTOT + n] = f2bf(gelu_exact(v + B0[n]));
          } else {
            long oidx = unperm_row(m) * 192 + n;
            outp[oidx] = f2bf(v + B0[n] + residf[oidx]);
          }
        }
      }
    }
  }
}

// ---------- GEMM K=768 (l2): A+B staged in LDS, BM=128 x BN=192 ----------
__global__ __launch_bounds__(256) void gemm2_kernel(
    const short* __restrict__ A, const short* __restrict__ Bt,
    const float* __restrict__ bias, const short* __restrict__ residb,
    float* __restrict__ outp) {
  __shared__ short As[128][72];
  __shared__ short Bs[192][72];
  const int tid = threadIdx.x;
  const int lane = tid & 63, wid = tid >> 6;
  const int lr = lane & 15, lg = lane >> 4;
  const int wm = wid >> 1, wn = wid & 1;  // 2x2 waves: 64 rows x 96 cols each
  const long m0 = (long)blockIdx.x * 128;

  f32x4 acc[4][6] = {};
#pragma unroll 1
  for (int kc = 0; kc < 12; ++kc) {
    __syncthreads();
#pragma unroll
    for (int p = 0; p < 4; ++p) {  // A: 128x64 = 1024 chunks
      int g = p * 256 + tid;
      int r = g >> 3, c = g & 7;
      *(float4*)(&As[r][c * 8]) =
          *(const float4*)(A + (m0 + r) * 768 + kc * 64 + c * 8);
    }
#pragma unroll
    for (int p = 0; p < 6; ++p) {  // B: 192x64 = 1536 chunks
      int g = p * 256 + tid;
      int n = g >> 3, c = g & 7;
      *(float4*)(&Bs[n][c * 8]) =
          *(const float4*)(Bt + (long)n * 768 + kc * 64 + c * 8);
    }
    __syncthreads();
#pragma unroll
    for (int ks = 0; ks < 2; ++ks) {
      bf16x8 a[4], b[6];
#pragma unroll
      for (int mf = 0; mf < 4; ++mf)
        a[mf] = *(const bf16x8*)(&As[wm * 64 + mf * 16 + lr][ks * 32 + lg * 8]);
#pragma unroll
      for (int nf = 0; nf < 6; ++nf)
        b[nf] = *(const bf16x8*)(&Bs[wn * 96 + nf * 16 + lr][ks * 32 + lg * 8]);
#pragma unroll
      for (int mf = 0; mf < 4; ++mf)
#pragma unroll
        for (int nf = 0; nf < 6; ++nf)
          acc[mf][nf] = __builtin_amdgcn_mfma_f32_16x16x32_bf16(
              a[mf], b[nf], acc[mf][nf], 0, 0, 0);
    }
  }
#pragma unroll
  for (int mf = 0; mf < 4; ++mf)
#pragma unroll
    for (int nf = 0; nf < 6; ++nf) {
      int n = wn * 96 + nf * 16 + lr;
      long rowb = m0 + wm * 64 + mf * 16 + lg * 4;
#pragma unroll
      for (int r = 0; r < 4; ++r) {
        long idx = (rowb + r) * 192 + n;
        outp[idx] = acc[mf][nf][r] + bias[n] + bf2f(residb[idx]);
      }
    }
}

// ---------- windowed attention: one wave per (window, head) ----------
// bid XCD-swizzled: all 6 heads of a window on the same XCD (L2 row reuse)
__global__ __launch_bounds__(64) void attn_kernel(const short* __restrict__ qkv,
                                                  const float* __restrict__ biasTab,
                                                  short* __restrict__ y) {
  __shared__ short vT[32][72];  // [d][token]
  __shared__ short P[64][72];   // [q][k]
  const int lane = threadIdx.x;
  const int bid = blockIdx.x;
  const int xcd = bid & 7;
  const int j = bid >> 3;            // 0..1535
  const int wglob = xcd * 256 + j / 6;  // 0..2047 (b*1024 + w)
  const int h = j % 6;
  const int w = wglob & 1023;
  const int wr = w >> 5, wc = w & 31;
  const long wbase = (long)wglob * 64;
  const int lr = lane & 15, lg = lane >> 4;

  bf16x8 aq[4], bk[4];
#pragma unroll
  for (int i = 0; i < 4; ++i) {
    long rq = wbase + i * 16 + lr;
    aq[i] = *(const bf16x8*)(qkv + rq * 576 + h * 32 + lg * 8);
    bk[i] = *(const bf16x8*)(qkv + rq * 576 + 192 + h * 32 + lg * 8);
  }
  {  // stage V transposed: vT[d][token]
    const short* vp = qkv + (wbase + lane) * 576 + 384 + h * 32;
#pragma unroll
    for (int q4 = 0; q4 < 4; ++q4) {
      bf16x8 vv = *(const bf16x8*)(vp + q4 * 8);
#pragma unroll
      for (int jj = 0; jj < 8; ++jj) vT[q4 * 8 + jj][lane] = vv[jj];
    }
  }

  f32x4 s[4][4] = {};
#pragma unroll
  for (int mi = 0; mi < 4; ++mi)
#pragma unroll
    for (int ni = 0; ni < 4; ++ni)
      s[mi][ni] = __builtin_amdgcn_mfma_f32_16x16x32_bf16(aq[mi], bk[ni],
                                                          s[mi][ni], 0, 0, 0);

  // softmax in log2 domain: S*scale*log2e + biasTab(prescaled) + mask*log2e
  const float SCL2 = 0.17677669529663687f * 1.4426950408889634f;
  const float MASKC = -144.26950408889634f;
  const bool edge = (wr == 31) || (wc == 31);
  int ridk[4] = {0, 0, 0, 0};
  if (edge) {
#pragma unroll
    for (int ni = 0; ni < 4; ++ni) {
      int k = ni * 16 + lr;
      int kh = wr * 8 + (k >> 3), kw = wc * 8 + (k & 7);
      ridk[ni] = 3 * ((kh < 248) ? 0 : ((kh < 252) ? 1 : 2)) +
                 ((kw < 248) ? 0 : ((kw < 252) ? 1 : 2));
    }
  }

  float rinv[4][4];
#pragma unroll
  for (int mi = 0; mi < 4; ++mi) {
#pragma unroll
    for (int r = 0; r < 4; ++r) {
      int q = mi * 16 + lg * 4 + r;
      const float* bp = biasTab + (h << 12) + (q << 6);
      int ridq = 0;
      if (edge) {
        int qh = wr * 8 + (q >> 3), qw = wc * 8 + (q & 7);
        ridq = 3 * ((qh < 248) ? 0 : ((qh < 252) ? 1 : 2)) +
               ((qw < 248) ? 0 : ((qw < 252) ? 1 : 2));
      }
      float lv[4];
      float mx = -1e30f;
#pragma unroll
      for (int ni = 0; ni < 4; ++ni) {
        float lvv = s[mi][ni][r] * SCL2 + bp[ni * 16 + lr];
        if (edge && ridq != ridk[ni]) lvv += MASKC;
        lv[ni] = lvv;
        mx = fmaxf(mx, lvv);
      }
#pragma unroll
      for (int m = 1; m < 16; m <<= 1) mx = fmaxf(mx, __shfl_xor(mx, m));
      float sum = 0.0f;
#pragma unroll
      for (int ni = 0; ni < 4; ++ni) {
        float p = exp2f(lv[ni] - mx);
        lv[ni] = p;
        sum += p;
      }
#pragma unroll
      for (int m = 1; m < 16; m <<= 1) sum += __shfl_xor(sum, m);
      rinv[mi][r] = 1.0f / sum;
#pragma unroll
      for (int ni = 0; ni < 4; ++ni) P[q][ni * 16 + lr] = f2bf(lv[ni]);
    }
  }
  __syncthreads();

  f32x4 o[4][2] = {};
#pragma unroll
  for (int ks = 0; ks < 2; ++ks) {
    bf16x8 ap[4], bv[2];
#pragma unroll
    for (int mi = 0; mi < 4; ++mi)
      ap[mi] = *(const bf16x8*)(&P[mi * 16 + lr][ks * 32 + lg * 8]);
#pragma unroll
    for (int ni = 0; ni < 2; ++ni)
      bv[ni] = *(const bf16x8*)(&vT[ni * 16 + lr][ks * 32 + lg * 8]);
#pragma unroll
    for (int mi = 0; mi < 4; ++mi)
#pragma unroll
      for (int ni = 0; ni < 2; ++ni)
        o[mi][ni] = __builtin_amdgcn_mfma_f32_16x16x32_bf16(ap[mi], bv[ni],
                                                            o[mi][ni], 0, 0, 0);
  }
#pragma unroll
  for (int mi = 0; mi < 4; ++mi) {
#pragma unroll
    for (int r = 0; r < 4; ++r) {
      int q = mi * 16 + lg * 4 + r;
      float ri = rinv[mi][r];
#pragma unroll
      for (int ni = 0; ni < 2; ++ni)
        y[(wbase + q) * 192 + h * 32 + ni * 16 + lr] = f2bf(o[mi][ni][r] * ri);
    }
  }
}

// ---------- depthwise 3x3 conv + GELU, weights in registers ----------
__global__ __launch_bounds__(256) void dwconv_kernel(const short* __restrict__ hbc,
                                                     const float* __restrict__ dww,
                                                     const float* __restrict__ dwb,
                                                     short* __restrict__ h2c,
                                                     int yh) {
  int t = blockIdx.x * 256 + threadIdx.x;  // over cg*px: 96*256 = 24576
  int cg = t % 96;
  int px = t / 96;
  int strip = blockIdx.y;  // 0..7 -> py = strip*16 .. +15

  float wv[9][8];
#pragma unroll
  for (int tap = 0; tap < 9; ++tap) {
    float4 a = *(const float4*)(dww + tap * 768 + cg * 8);
    float4 b = *(const float4*)(dww + tap * 768 + cg * 8 + 4);
    wv[tap][0] = a.x; wv[tap][1] = a.y; wv[tap][2] = a.z; wv[tap][3] = a.w;
    wv[tap][4] = b.x; wv[tap][5] = b.y; wv[tap][6] = b.z; wv[tap][7] = b.w;
  }
  float bias[8];
  {
    float4 a = *(const float4*)(dwb + cg * 8);
    float4 b = *(const float4*)(dwb + cg * 8 + 4);
    bias[0] = a.x; bias[1] = a.y; bias[2] = a.z; bias[3] = a.w;
    bias[4] = b.x; bias[5] = b.y; bias[6] = b.z; bias[7] = b.w;
  }

#pragma unroll 2
  for (int pp = 0; pp < 16; ++pp) {
    int py = strip * 16 + pp;
    int ybase = yh * 128 + py;
    float acc[8];
#pragma unroll
    for (int j = 0; j < 8; ++j) acc[j] = bias[j];
#pragma unroll
    for (int dy = 0; dy < 3; ++dy) {
      int yy = ybase + dy - 1;
      if (yy < 0 || yy > 255) continue;
      int slot = py + dy;
#pragma unroll
      for (int dx = 0; dx < 3; ++dx) {
        int xx = px + dx - 1;
        if (xx < 0 || xx > 255) continue;
        bf16x8 hv = *(const bf16x8*)(hbc + ((long)slot * 256 + xx) * 768 + cg * 8);
#pragma unroll
        for (int j = 0; j < 8; ++j) acc[j] += bf2f(hv[j]) * wv[dy * 3 + dx][j];
      }
    }
    bf16x8 ov;
#pragma unroll
    for (int j = 0; j < 8; ++j) ov[j] = f2bf(gelu_exact(acc[j]));
    *(bf16x8*)(h2c + ((long)py * 256 + px) * 768 + cg * 8) = ov;
  }
}

// ---------- launch ----------
extern "C" void kernel_launch(void* const* d_in, const int* in_sizes, int n_in,
                              void* d_out, int out_size, void* d_ws, size_t ws_size,
                              hipStream_t stream) {
  const float* x = (const float*)d_in[0];
  const float* n1w = (const float*)d_in[1];
  const float* n1b = (const float*)d_in[2];
  const float* q_w = (const float*)d_in[3];
  const float* q_b = (const float*)d_in[4];
  const float* kv_w = (const float*)d_in[5];
  const float* kv_b = (const float*)d_in[6];
  const float* rpb = (const float*)d_in[7];
  const float* proj_w = (const float*)d_in[8];
  const float* proj_b = (const float*)d_in[9];
  const float* n2w = (const float*)d_in[10];
  const float* n2b = (const float*)d_in[11];
  const float* l1_w = (const float*)d_in[12];
  const float* l1_b = (const float*)d_in[13];
  const float* dw_w = (const float*)d_in[14];
  const float* dw_b = (const float*)d_in[15];
  const float* l2_w = (const float*)d_in[16];
  const float* l2_b = (const float*)d_in[17];
  float* out = (float*)d_out;

  // ---- workspace: total ~252.6 MB ----
  char* ws = (char*)d_ws;
  short* xn = (short*)ws;                     // [0,48M): xn(win) -> yb -> xn2
  short* qkv = (short*)(ws + 50331648);       // [48M,192M) window order
  short* hbc = (short*)(ws + 50331648);       // reuse: 51,118,080 B
  short* h2c = (short*)(ws + 101449728);      // 50,331,648 B (ends 144.7M)
  short* x2bf = (short*)(ws + 201326592);     // [192M,240M) token order bf16
  short* bt1 = (short*)(ws + 251658240);      // [576][192]
  short* bt2 = bt1 + 110592;                  // [192][192]
  short* bt3 = bt2 + 36864;                   // [768][192]
  short* bt4 = bt3 + 147456;                  // [192][768] ends 252,542,976
  float* biasTab = (float*)(ws + 252542976);  // 6*64*64 f32 = 98,304 B
  short* yb = xn;
  short* xn2 = xn;

  wprep_kernel<<<144, 256, 0, stream>>>(q_w, bt1, 192, 192);
  wprep_kernel<<<288, 256, 0, stream>>>(kv_w, bt1 + 36864, 192, 384);
  wprep_kernel<<<144, 256, 0, stream>>>(proj_w, bt2, 192, 192);
  wprep_kernel<<<576, 256, 0, stream>>>(l1_w, bt3, 192, 768);
  wprep_kernel<<<576, 256, 0, stream>>>(l2_w, bt4, 768, 192);
  bias_prep<<<96, 256, 0, stream>>>(rpb, biasTab);

  ln1_kernel<<<32768, 256, 0, stream>>>(x, n1w, n1b, xn);
  // qkv: 1024 m-tiles, 9 n-blocks, iters=8; grid 8 xcd * 16 mg * 9 n = 1152
  gemm1_kernel<576, 0><<<1152, 256, 0, stream>>>(xn, bt1, q_b, kv_b, nullptr,
                                                 qkv, 9, 16, 8, 1024);
  attn_kernel<<<12288, 64, 0, stream>>>(qkv, biasTab, yb);
  // proj: 1024 m-tiles, 3 n-blocks, iters=8; grid 8*16*3 = 384
  gemm1_kernel<192, 3><<<384, 256, 0, stream>>>(yb, bt2, proj_b, nullptr, x,
                                                x2bf, 3, 16, 8, 1024);
  ln2_kernel<<<32768, 256, 0, stream>>>(x2bf, n2w, n2b, xn2);

  // LeFF in 4 chunks: (batch b, y-half yh), 129 rows with 1-row conv halo
  for (int c = 0; c < 4; ++c) {
    int b = c >> 1, yh = c & 1;
    int ystart = yh ? 127 : 0;
    int s0 = yh ? 0 : 1;
    long tok0 = (long)b * 65536 + (long)ystart * 256;
    long ooff = ((long)b * 65536 + (long)yh * 32768) * 192;
    // l1: 258 m-tiles (pad to 288), 12 n-blocks, iters=4; grid 8*9*12 = 864
    gemm1_kernel<768, 2><<<864, 256, 0, stream>>>(
        xn2 + tok0 * 192, bt3, l1_b, nullptr, nullptr,
        hbc + (long)s0 * 196608, 12, 9, 4, 258);
    dwconv_kernel<<<dim3(96, 8), 256, 0, stream>>>(hbc, dw_w, dw_b, h2c, yh);
    // l2: 256 m-tiles, full N=192 per block
    gemm2_kernel<<<256, 256, 0, stream>>>(h2c, bt4, l2_b, x2bf + ooff,
                                          out + ooff);
  }
}